// Round 19
// baseline (601.847 us; speedup 1.0000x reference)
//
#include <hip/hip_runtime.h>
#include <hip/hip_bf16.h>

typedef float f32x4 __attribute__((ext_vector_type(4)));
typedef short bf16x8 __attribute__((ext_vector_type(8)));
typedef unsigned short u16;

#define SEQ    512
#define DIM    2048
#define NHEAD  16
#define HDIM   128
#define BATCH  4
#define BTOK   2048
#define FFDIM  8192
#define DSZ    ((long)BTOK*DIM)       // 4,194,304 elements (2^22)
#define QKVN   (3*DIM)                // 6144
#define QKVSZ  ((long)BTOK*QKVN)
#define ISS    0.08838834764831845f   // 1/sqrt(128)

__device__ __forceinline__ u16 f2bf(float f){
  union{float fv;unsigned u;}c;c.fv=f;
  unsigned r=c.u+0x7FFFu+((c.u>>16)&1u); return (u16)(r>>16);
}
__device__ __forceinline__ float bf2f(u16 v){
  union{unsigned u;float f;}c;c.u=((unsigned)v)<<16;return c.f;
}
__device__ __forceinline__ float pow103(float t){
  return __builtin_amdgcn_exp2f(__builtin_amdgcn_logf(t)*(10.0f/3.0f));
}

// async global->LDS, 16B per lane, LDS dest = wave-uniform base + lane*16
#define GLD16(g,l) __builtin_amdgcn_global_load_lds( \
    (const __attribute__((address_space(1))) unsigned int*)(g), \
    (__attribute__((address_space(3))) unsigned int*)(l), 16, 0, 0)

#define MF(a,b,c) __builtin_amdgcn_mfma_f32_16x16x32_bf16(a,b,c,0,0,0)
#define VMW(n) do{ asm volatile("s_waitcnt vmcnt(" #n ")" ::: "memory"); \
                   __builtin_amdgcn_sched_barrier(0); }while(0)
#define LGKM0() do{ asm volatile("s_waitcnt lgkmcnt(0)" ::: "memory"); \
                    __builtin_amdgcn_sched_barrier(0); }while(0)
#define BARR() do{ asm volatile("" ::: "memory"); __builtin_amdgcn_s_barrier(); \
                   asm volatile("" ::: "memory"); }while(0)

// ---------------------------------------------------------------------------
// gemm8p: m201-style 256x256 block, 8 waves (wave tile 128x64, acc 8x4),
// BK=32, 3 K-tile LDS buffers (96 KiB) -> stage tile t+2 during t (loads
// get ~2 K-tiles to land). 2 quadrant phases per K-tile:
//   ph0 (rows 0-63):  8 ds_read (af x4 + bv x4) ; STG A-unit(t+2) ; BARR ;
//                     lgkm0 ; setprio ; 16 MFMA ; setprio ; BARR
//   ph1 (rows 64-127):4 ds_read (af x4; bv REUSED) ; STG B-unit(t+2) ;
//                     VMW(4) [certify t+1] ; BARR ; lgkm0 ; 16 MFMA ; BARR
// One counted vmcnt per K-tile, never 0 mid-loop. Staging unit/swizzle
// identical to the R5-verified gemm8 (chunk=q*8+w over 256 rows).
// A m-major, B n-major/K-contig. M,N mult 256, K mult 32 (NT>=2).
// ---------------------------------------------------------------------------
__global__ __launch_bounds__(512, 2)
void gemm8p(const u16* __restrict__ A, int lda, long sAo,
            const u16* __restrict__ B, int ldb, long sBo,
            u16* __restrict__ C, int ldc, long sCo,
            const float* __restrict__ bias, long sbias,
            int K, int relu)
{
  __shared__ __align__(16) u16 sm[49152];     // 96 KiB = 3 x (A 16K + B 16K)
  char* smb = (char*)sm;

  int gx = gridDim.x, gy = gridDim.y;
  int nwg = gx*gy*gridDim.z;
  int flat = (blockIdx.z*gy + blockIdx.y)*gx + blockIdx.x;
  int cpx = nwg >> 3; flat = (flat & 7)*cpx + (flat >> 3);
  int by = flat % gy; int tq = flat / gy; int bx = tq % gx; int bz = tq / gx;

  const u16* Ab = A + (long)bz*sAo;
  const u16* Bb = B + (long)bz*sBo;
  int m0 = by*256, n0 = bx*256;

  int tid = threadIdx.x, lane = tid & 63, w = tid >> 6;
  int wrow = (w>>2)*128, wn = (w&3)*64;
  int lr = lane & 15, lg = lane >> 4;

  // staging: unit = one operand's K-tile = 256 rows x 32 cols = 16 KiB.
  // 16 chunks of 1 KiB (16 rows x 32 cols); wave w stages chunks w, w+8.
  int stR[2], stC[2], ldsch[2];
  #pragma unroll
  for (int q = 0; q < 2; q++) {
    int chunk = q*8 + w;
    int r = chunk*16 + (lane>>2);
    int c = (lane&3)*16;
    int Rz = r ^ ((r>>2)&1);
    int Cz = c ^ ((((r>>2)^r)&1)<<4) ^ (((r>>1)&1)<<5);
    stR[q] = Rz; stC[q] = Cz>>1;
    ldsch[q] = chunk*1024;
  }

  int aoff = ((wrow + lr)*64 + lg*16) ^ ((lane&7)<<4);
  int boff = ((wn  + lr)*64 + lg*16) ^ ((lane&7)<<4);

  f32x4 acc[8][4] = {};
  int NT = K >> 5;

  auto STG = [&](int buf, int op, int kt) {   // 2 gld_lds
    const u16* gp = op ? Bb : Ab;
    int ld   = op ? ldb : lda;
    int base = op ? n0 : m0;
    int kcol = kt*32;
    #pragma unroll
    for (int q = 0; q < 2; q++) {
      const u16* src = gp + (long)(base + stR[q])*ld + kcol + stC[q];
      char* dst = smb + buf*32768 + op*16384 + ldsch[q];
      GLD16(src, dst);
    }
  };

  // prologue: tiles 0,1 staged (buf0,buf1); certify tile0 (tile1 in flight)
  STG(0,0,0); STG(0,1,0);
  STG(1,0,1); STG(1,1,1);
  VMW(4);
  BARR();

  int buf = 0;
  for (int t = 0; t < NT; t++) {
    char* Ax = smb + buf*32768;
    char* Bx = Ax + 16384;
    int b2 = buf + 2; if (b2 >= 3) b2 -= 3;   // buf of tile t+2
    bool st = (t+2 < NT);

    bf16x8 af[4], bv[4];

    // ---- phase 0: quadrant rows 0-63
    #pragma unroll
    for (int i = 0; i < 4; i++) af[i] = *(const bf16x8*)(Ax + aoff + i*1024);
    #pragma unroll
    for (int j = 0; j < 4; j++) bv[j] = *(const bf16x8*)(Bx + boff + j*1024);
    if (st) STG(b2, 0, t+2);
    BARR();
    LGKM0();
    __builtin_amdgcn_s_setprio(1);
    #pragma unroll
    for (int i = 0; i < 4; i++) {
      acc[i][0] = MF(af[i], bv[0], acc[i][0]);
      acc[i][1] = MF(af[i], bv[1], acc[i][1]);
      acc[i][2] = MF(af[i], bv[2], acc[i][2]);
      acc[i][3] = MF(af[i], bv[3], acc[i][3]);
    }
    __builtin_amdgcn_s_setprio(0);
    BARR();

    // ---- phase 1: quadrant rows 64-127 (bv reused from registers)
    #pragma unroll
    for (int i = 0; i < 4; i++) af[i] = *(const bf16x8*)(Ax + aoff + (4+i)*1024);
    if (st) { STG(b2, 1, t+2); VMW(4); }       // certify tile t+1
    else if (t+1 < NT) { VMW(0); }             // tail: certify t+1, none in flight
    BARR();
    LGKM0();
    __builtin_amdgcn_s_setprio(1);
    #pragma unroll
    for (int i = 0; i < 4; i++) {
      acc[4+i][0] = MF(af[i], bv[0], acc[4+i][0]);
      acc[4+i][1] = MF(af[i], bv[1], acc[4+i][1]);
      acc[4+i][2] = MF(af[i], bv[2], acc[4+i][2]);
      acc[4+i][3] = MF(af[i], bv[3], acc[4+i][3]);
    }
    __builtin_amdgcn_s_setprio(0);
    BARR();

    buf++; if (buf == 3) buf = 0;
  }

  // epilogue: bf16 + bias + optional relu
  u16* Cb = C + (long)bz*sCo;
  #pragma unroll
  for (int j = 0; j < 4; j++) {
    int col = n0 + wn + j*16 + lr;
    float bv2 = bias ? bias[bz*sbias + col] : 0.0f;
    #pragma unroll
    for (int i = 0; i < 8; i++) {
      #pragma unroll
      for (int e = 0; e < 4; e++) {
        int row = m0 + wrow + i*16 + lg*4 + e;
        float v = acc[i][j][e] + bv2;
        if (relu) v = fmaxf(v, 0.0f);
        Cb[(long)row*ldc + col] = f2bf(v);
      }
    }
  }
}

// ---------------------------------------------------------------------------
// gemm4: 128x128 tile, BK=32, 4 waves, 3-deep pipeline, 48 KiB LDS
// (3 blocks/CU). C offset = zo*sCo + zi*sCi (supports per-head PV output).
// ---------------------------------------------------------------------------
__global__ __launch_bounds__(256, 3)
void gemm4(const u16* __restrict__ A, int lda, long sAo, long sAi,
           const u16* __restrict__ B, int ldb, long sBo, long sBi,
           void* __restrict__ C, int ldc, long sCo, long sCi, int outbf,
           const float* __restrict__ bias, long sbias,
           int K, int hdiv, int relu)
{
  __shared__ __align__(16) u16 sm[24576];     // 48 KiB
  char* smb = (char*)sm;

  int gx = gridDim.x, gy = gridDim.y;
  int nwg = gx*gy*gridDim.z;
  int flat = (blockIdx.z*gy + blockIdx.y)*gx + blockIdx.x;
  int cpx = nwg >> 3; flat = (flat & 7)*cpx + (flat >> 3);
  int by = flat % gy; int tq = flat / gy; int bx = tq % gx; int bz = tq / gx;

  int zo = bz / hdiv, zi = bz - zo*hdiv;
  const u16* Ab = A + (long)zo*sAo + (long)zi*sAi;
  const u16* Bb = B + (long)zo*sBo + (long)zi*sBi;
  int m0 = by*128, n0 = bx*128;

  int tid = threadIdx.x, lane = tid & 63, w = tid >> 6;
  int wrow = (w>>1)*64, wn = (w&1)*64;
  int lr = lane & 15, lg = lane >> 4;

  int stR[2], stC[2], ldsch[2];
  #pragma unroll
  for (int q = 0; q < 2; q++) {
    int chunk = q*4 + w;
    int r = chunk*16 + (lane>>2);
    int c = (lane&3)*16;
    int Rz = r ^ ((r>>2)&1);
    int Cz = c ^ ((((r>>2)^r)&1)<<4) ^ (((r>>1)&1)<<5);
    stR[q] = Rz; stC[q] = Cz>>1;
    ldsch[q] = chunk*1024;
  }

  int aoff = ((wrow + lr)*64 + lg*16) ^ ((lane&7)<<4);
  int boff = ((wn  + lr)*64 + lg*16) ^ ((lane&7)<<4);

  f32x4 acc[4][4] = {};
  int NT = K >> 5;

  auto STG = [&](int buf, int op, int kt) {
    const u16* gp = op ? Bb : Ab;
    int ld   = op ? ldb : lda;
    int base = op ? n0 : m0;
    int kcol = kt*32;
    #pragma unroll
    for (int q = 0; q < 2; q++) {
      const u16* src = gp + (long)(base + stR[q])*ld + kcol + stC[q];
      char* dst = smb + buf*16384 + op*8192 + ldsch[q];
      GLD16(src, dst);
    }
  };

  STG(0,0,0); STG(0,1,0);
  if (NT > 1) { STG(1,0,1); STG(1,1,1); }

  int buf = 0;
  for (int t = 0; t < NT; t++) {
    char* Ax = smb + buf*16384;
    char* Bx = smb + buf*16384 + 8192;

    if (t+2 < NT) {
      int nb = buf + 2; if (nb >= 3) nb -= 3;
      STG(nb,0,t+2); STG(nb,1,t+2);
      VMW(8);
    } else if (t+1 < NT) { VMW(4); }
    else                 { VMW(0); }
    BARR();

    bf16x8 af[4], bv[4];
    #pragma unroll
    for (int i = 0; i < 4; i++) af[i] = *(const bf16x8*)(Ax + aoff + i*1024);
    #pragma unroll
    for (int j = 0; j < 4; j++) bv[j] = *(const bf16x8*)(Bx + boff + j*1024);
    LGKM0();
    __builtin_amdgcn_s_setprio(1);
    #pragma unroll
    for (int i = 0; i < 4; i++) {
      acc[i][0] = MF(af[i], bv[0], acc[i][0]);
      acc[i][1] = MF(af[i], bv[1], acc[i][1]);
      acc[i][2] = MF(af[i], bv[2], acc[i][2]);
      acc[i][3] = MF(af[i], bv[3], acc[i][3]);
    }
    __builtin_amdgcn_s_setprio(0);
    BARR();
    buf++; if (buf == 3) buf = 0;
  }

  long coff = (long)zo*sCo + (long)zi*sCi;
  if (outbf) {
    u16* Cb = (u16*)C + coff;
    #pragma unroll
    for (int j = 0; j < 4; j++) {
      int col = n0 + wn + j*16 + lr;
      float bv2 = bias ? bias[zo*sbias + col] : 0.0f;
      #pragma unroll
      for (int i = 0; i < 4; i++) {
        #pragma unroll
        for (int e = 0; e < 4; e++) {
          int row = m0 + wrow + i*16 + lg*4 + e;
          float v = acc[i][j][e] + bv2;
          if (relu) v = fmaxf(v, 0.0f);
          Cb[(long)row*ldc + col] = f2bf(v);
        }
      }
    }
  } else {
    float* Cb = (float*)C + coff;
    #pragma unroll
    for (int j = 0; j < 4; j++) {
      int col = n0 + wn + j*16 + lr;
      #pragma unroll
      for (int i = 0; i < 4; i++) {
        #pragma unroll
        for (int e = 0; e < 4; e++) {
          int row = m0 + wrow + i*16 + lg*4 + e;
          Cb[(long)row*ldc + col] = acc[i][j][e];
        }
      }
    }
  }
}

// ---------------------------------------------------------------------------
// qkprobs_both: grid (128, 16): x = br*64+head, y = q-tile (BM=32).
// 40KB LDS, launch_bounds(256,2) -> no spill (R18: WRITE=64MB exactly).
// ---------------------------------------------------------------------------
__global__ __launch_bounds__(256, 2)
void qkprobs_both(const u16* __restrict__ QKVp,
                  const float* __restrict__ maskI, const float* __restrict__ maskE,
                  u16* __restrict__ Pall)
{
  __shared__ __align__(16) u16 sm[20480];      // 40 KiB: A 8K + K 32K
  char* smb = (char*)sm;

  int z2 = blockIdx.x;
  int m0 = blockIdx.y*32;
  int br = z2 >> 6, z = z2 & 63;
  int b  = z >> 4, h = z & 15;
  const float* maskp = br ? maskE : maskI;
  const u16* Qb = QKVp + (long)br*QKVSZ + (long)b*SEQ*QKVN + h*HDIM;
  const u16* Kb = Qb + DIM;
  u16* P = Pall + (long)br*64*SEQ*SEQ;

  int tid = threadIdx.x, lane = tid & 63, w = tid >> 6;
  int lr = lane & 15, lg = lane >> 4;
  int wn = w*128;

  int rl = lane >> 2;
  int cb = (lane & 3)*16;

  int aoff = (lr*64 + lg*16) ^ ((lane&7)<<4);
  int boff = ((wn + lr)*64 + lg*16) ^ ((lane&7)<<4);

  auto stgA = [&](int kt) {
    int r = (w&1)*16 + rl;
    int Rz = r ^ ((r>>2)&1);
    int Cz = cb ^ ((((r>>2)^r)&1)<<4) ^ (((r>>1)&1)<<5);
    GLD16(Qb + (long)(m0+Rz)*QKVN + kt*32 + (Cz>>1), smb + kt*2048 + (w&1)*1024);
  };
  auto stgB = [&](int kt) {
    #pragma unroll
    for (int q = 0; q < 8; q++) {
      int chunk = q*4 + w;
      int r = chunk*16 + rl;
      int Rz = r ^ ((r>>2)&1);
      int Cz = cb ^ ((((r>>2)^r)&1)<<4) ^ (((r>>1)&1)<<5);
      GLD16(Kb + (long)Rz*QKVN + kt*32 + (Cz>>1),
            smb + 8192 + chunk*1024);
    }
  };

  f32x4 acc[2][8] = {};                        // 64 VGPRs

  stgA(0); stgA(1); stgA(2); stgA(3);
  stgB(0);

  #pragma unroll
  for (int kt = 0; kt < 4; kt++) {
    VMW(0);
    BARR();
    char* Bx = smb + 8192;
    bf16x8 af[2], bv[8];
    #pragma unroll
    for (int i = 0; i < 2; i++) af[i] = *(const bf16x8*)(smb + kt*2048 + aoff + i*1024);
    #pragma unroll
    for (int j = 0; j < 8; j++) bv[j] = *(const bf16x8*)(Bx + boff + j*1024);
    LGKM0();
    BARR();
    if (kt < 3) stgB(kt+1);
    __builtin_amdgcn_s_setprio(1);
    #pragma unroll
    for (int i = 0; i < 2; i++)
      #pragma unroll
      for (int j = 0; j < 8; j++)
        acc[i][j] = MF(af[i], bv[j], acc[i][j]);
    __builtin_amdgcn_s_setprio(0);
  }

  float* redA = (float*)smb;
  float* redB = (float*)(smb + 512);

  float rmax[8];
  #pragma unroll
  for (int s = 0; s < 8; s++) rmax[s] = -3.4e38f;
  #pragma unroll
  for (int i = 0; i < 2; i++) {
    #pragma unroll
    for (int e = 0; e < 4; e++) {
      int row = i*16 + lg*4 + e;
      const float* mp = maskp + (long)(m0+row)*SEQ + wn + lr;
      #pragma unroll
      for (int j = 0; j < 8; j++) {
        float v = acc[i][j][e]*ISS + mp[j*16];
        acc[i][j][e] = v;
        rmax[i*4+e] = fmaxf(rmax[i*4+e], v);
      }
    }
  }
  #pragma unroll
  for (int s = 0; s < 8; s++)
    #pragma unroll
    for (int o = 1; o < 16; o <<= 1) rmax[s] = fmaxf(rmax[s], __shfl_xor(rmax[s], o));
  if (lr == 0) {
    #pragma unroll
    for (int i = 0; i < 2; i++)
      #pragma unroll
      for (int e = 0; e < 4; e++) redA[w*32 + i*16 + lg*4 + e] = rmax[i*4+e];
  }
  BARR();
  #pragma unroll
  for (int i = 0; i < 2; i++)
    #pragma unroll
    for (int e = 0; e < 4; e++) {
      int row = i*16 + lg*4 + e;
      rmax[i*4+e] = fmaxf(fmaxf(redA[row], redA[32+row]),
                          fmaxf(redA[64+row], redA[96+row]));
    }
  BARR();

  float inv[8];

  if (br) {
    #pragma unroll
    for (int i = 0; i < 2; i++)
      #pragma unroll
      for (int j = 0; j < 8; j++)
        #pragma unroll
        for (int e = 0; e < 4; e++)
          acc[i][j][e] = (acc[i][j][e] - rmax[i*4+e])*0.3f;

    float lo[8];
    #pragma unroll
    for (int s = 0; s < 8; s++) lo[s] = -1.0f;
    float half = 0.5f;

    #pragma unroll 1
    for (int it = 0; it < 5; it++) {
      float ps[8];
      #pragma unroll
      for (int s = 0; s < 8; s++) ps[s] = 0.0f;
      #pragma unroll
      for (int i = 0; i < 2; i++)
        #pragma unroll
        for (int e = 0; e < 4; e++) {
          float mid = lo[i*4+e] + half;
          #pragma unroll
          for (int j = 0; j < 8; j++) {
            float t = acc[i][j][e] - mid;
            if (t > 0.0f) ps[i*4+e] += pow103(t);
          }
        }
      #pragma unroll
      for (int s = 0; s < 8; s++)
        #pragma unroll
        for (int o = 1; o < 16; o <<= 1) ps[s] += __shfl_xor(ps[s], o);
      if (lr == 0) {
        #pragma unroll
        for (int i = 0; i < 2; i++)
          #pragma unroll
          for (int e = 0; e < 4; e++) redA[w*32 + i*16 + lg*4 + e] = ps[i*4+e];
      }
      BARR();
      #pragma unroll
      for (int i = 0; i < 2; i++)
        #pragma unroll
        for (int e = 0; e < 4; e++) {
          int row = i*16 + lg*4 + e, s = i*4+e;
          float tot = redA[row] + redA[32+row] + redA[64+row] + redA[96+row];
          if (tot > 1.0f) lo[s] += half;
        }
      BARR();
      half *= 0.5f;
    }

    #pragma unroll 1
    for (int it = 0; it < 3; it++) {
      float ps[8], pd[8];
      #pragma unroll
      for (int s = 0; s < 8; s++) { ps[s] = 0.0f; pd[s] = 0.0f; }
      #pragma unroll
      for (int i = 0; i < 2; i++)
        #pragma unroll
        for (int e = 0; e < 4; e++) {
          float tv = lo[i*4+e];
          #pragma unroll
          for (int j = 0; j < 8; j++) {
            float t = acc[i][j][e] - tv;
            if (t > 0.0f) {
              float w7 = __builtin_amdgcn_exp2f(__builtin_amdgcn_logf(t)*(7.0f/3.0f));
              pd[i*4+e] += w7; ps[i*4+e] += w7*t;
            }
          }
        }
      #pragma unroll
      for (int s = 0; s < 8; s++)
        #pragma unroll
        for (int o = 1; o < 16; o <<= 1) {
          ps[s] += __shfl_xor(ps[s], o);
          pd[s] += __shfl_xor(pd[s], o);
        }
      if (lr == 0) {
        #pragma unroll
        for (int i = 0; i < 2; i++)
          #pragma unroll
          for (int e = 0; e < 4; e++) {
            redA[w*32 + i*16 + lg*4 + e] = ps[i*4+e];
            redB[w*32 + i*16 + lg*4 + e] = pd[i*4+e];
          }
      }
      BARR();
      #pragma unroll
      for (int i = 0; i < 2; i++)
        #pragma unroll
        for (int e = 0; e < 4; e++) {
          int row = i*16 + lg*4 + e, s = i*4+e;
          float st = redA[row] + redA[32+row] + redA[64+row] + redA[96+row];
          float dt = redB[row] + redB[32+row] + redB[64+row] + redB[96+row];
          lo[s] += (st - 1.0f) / ((10.0f/3.0f)*dt + 1e-30f);
        }
      BARR();
    }

    float ps[8];
    #pragma unroll
    for (int s = 0; s < 8; s++) ps[s] = 0.0f;
    #pragma unroll
    for (int i = 0; i < 2; i++)
      #pragma unroll
      for (int e = 0; e < 4; e++) {
        float tv = lo[i*4+e];
        #pragma unroll
        for (int j = 0; j < 8; j++) {
          float t = acc[i][j][e] - tv;
          float p = (t > 0.0f) ? pow103(t) : 0.0f;
          acc[i][j][e] = p;
          ps[i*4+e] += p;
        }
      }
    #pragma unroll
    for (int s = 0; s < 8; s++)
      #pragma unroll
      for (int o = 1; o < 16; o <<= 1) ps[s] += __shfl_xor(ps[s], o);
    if (lr == 0) {
      #pragma unroll
      for (int i = 0; i < 2; i++)
        #pragma unroll
        for (int e = 0; e < 4; e++) redA[w*32 + i*16 + lg*4 + e] = ps[i*4+e];
    }
    BARR();
    #pragma unroll
    for (int i = 0; i < 2; i++)
      #pragma unroll
      for (int e = 0; e < 4; e++) {
        int row = i*16 + lg*4 + e;
        inv[i*4+e] = 1.0f/(redA[row] + redA[32+row] + redA[64+row] + redA[96+row] + 1e-12f);
      }
  } else {
    float ps[8];
    #pragma unroll
    for (int s = 0; s < 8; s++) ps[s] = 0.0f;
    #pragma unroll
    for (int i = 0; i < 2; i++)
      #pragma unroll
      for (int e = 0; e < 4; e++) {
        float mx = rmax[i*4+e];
        #pragma unroll
        for (int j = 0; j < 8; j++) {
          float p = __expf(acc[i][j][e] - mx);
          acc[i][j][e] = p;
          ps[i*4+e] += p;
        }
      }
    #pragma unroll
    for (int s = 0; s < 8; s++)
      #pragma unroll
      for (int o = 1; o < 16; o <<= 1) ps[s] += __shfl_xor(ps[s], o);
    if (lr == 0) {
      #pragma unroll
      for (int i = 0; i < 2; i++)
        #pragma unroll
        for (int e = 0; e < 4; e++) redA[w*32 + i*16 + lg*4 + e] = ps[i*4+e];
    }
    BARR();
    #pragma unroll
    for (int i = 0; i < 2; i++)
      #pragma unroll
      for (int e = 0; e < 4; e++) {
        int row = i*16 + lg*4 + e;
        inv[i*4+e] = 1.0f/(redA[row] + redA[32+row] + redA[64+row] + redA[96+row]);
      }
  }

  // ---- LDS repack + coalesced copy-out ----
  BARR();
  char* rp = smb + 8192;
  #pragma unroll
  for (int i = 0; i < 2; i++)
    #pragma unroll
    for (int e = 0; e < 4; e++) {
      int r = i*16 + lg*4 + e;
      float sc = inv[i*4+e];
      #pragma unroll
      for (int j = 0; j < 8; j++) {
        int cbyt = (wn + j*16 + lr)*2;
        *(u16*)(rp + r*1024 + (cbyt ^ ((r&7)<<4))) = f2bf(acc[i][j][e]*sc);
      }
    }
  BARR();
  u16* Pb = P + ((long)z*SEQ + m0)*SEQ;
  #pragma unroll
  for (int chunk = 0; chunk < 8; chunk++) {
    int p = chunk*4096 + tid*16;
    int row = p >> 10, cb2 = p & 1023;
    bf16x8 v = *(const bf16x8*)(rp + row*1024 + (cb2 ^ ((row&7)<<4)));
    *(bf16x8*)((char*)Pb + p) = v;
  }
}

// ---------------------------------------------------------------------------
// split-K reduce
// ---------------------------------------------------------------------------
__global__ __launch_bounds__(256)
void redk(const float* __restrict__ Pp, int nk, const float* __restrict__ bias,
          u16* __restrict__ out)
{
  long i = ((long)blockIdx.x*256 + threadIdx.x)*8;
  long z = i >> 22;
  int  n = (int)(i & 2047);
  float v[8] = {};
  for (int k = 0; k < nk; k++) {
    const float* s = Pp + (z*nk + k)*DSZ + (i & (DSZ-1));
    f32x4 aa = *(const f32x4*)s, bb = *(const f32x4*)(s+4);
    v[0]+=aa.x; v[1]+=aa.y; v[2]+=aa.z; v[3]+=aa.w;
    v[4]+=bb.x; v[5]+=bb.y; v[6]+=bb.z; v[7]+=bb.w;
  }
  f32x4 b0 = *(const f32x4*)&bias[z*2048 + n], b1 = *(const f32x4*)&bias[z*2048 + n + 4];
  float bv[8] = {b0.x,b0.y,b0.z,b0.w,b1.x,b1.y,b1.z,b1.w};
  u16 w[8] __attribute__((aligned(16)));
  #pragma unroll
  for (int j = 0; j < 8; j++) w[j] = f2bf(v[j] + bv[j]);
  *(bf16x8*)&out[i] = *(bf16x8*)w;
}

// ---------------------------------------------------------------------------
// fp32 W[k][n] -> bf16 Wt[n][k]; wtrans6 batches up to 6 same-shape sources
// ---------------------------------------------------------------------------
struct P6 { const float* p[6]; };

__global__ __launch_bounds__(256)
void wtrans6(P6 srcs, int ldw, u16* __restrict__ Wt, long dstStride, int ldt)
{
  __shared__ u16 t[64][72];
  const float* W = srcs.p[blockIdx.z];
  u16* Wd = Wt + (long)blockIdx.z*dstStride;
  int tid = threadIdx.x, r = tid >> 2, c0 = (tid & 3)*16;
  long gr = (long)blockIdx.y*64 + r, gc = (long)blockIdx.x*64 + c0;
  #pragma unroll
  for (int u = 0; u < 16; u += 4) {
    f32x4 v = *(const f32x4*)&W[gr*ldw + gc + u];
    t[r][c0+u+0]=f2bf(v.x); t[r][c0+u+1]=f2bf(v.y);
    t[r][c0+u+2]=f2bf(v.z); t[r][c0+u+3]=f2bf(v.w);
  }
  __syncthreads();
  u16 o[16] __attribute__((aligned(16)));
  #pragma unroll
  for (int u = 0; u < 16; u++) o[u] = t[c0+u][r];
  u16* dst = &Wd[(long)(blockIdx.x*64 + r)*ldt + blockIdx.y*64 + c0];
  *(bf16x8*)&dst[0] = *(bf16x8*)&o[0];
  *(bf16x8*)&dst[8] = *(bf16x8*)&o[8];
}

__global__ __launch_bounds__(256)
void wtrans(const float* __restrict__ W, int ldw, u16* __restrict__ Wt, int ldt)
{
  __shared__ u16 t[64][72];
  int tid = threadIdx.x, r = tid >> 2, c0 = (tid & 3)*16;
  long gr = (long)blockIdx.y*64 + r, gc = (long)blockIdx.x*64 + c0;
  #pragma unroll
  for (int u = 0; u < 16; u += 4) {
    f32x4 v = *(const f32x4*)&W[gr*ldw + gc + u];
    t[r][c0+u+0]=f2bf(v.x); t[r][c0+u+1]=f2bf(v.y);
    t[r][c0+u+2]=f2bf(v.z); t[r][c0+u+3]=f2bf(v.w);
  }
  __syncthreads();
  u16 o[16] __attribute__((aligned(16)));
  #pragma unroll
  for (int u = 0; u < 16; u++) o[u] = t[c0+u][r];
  u16* dst = &Wt[(long)(blockIdx.x*64 + r)*ldt + blockIdx.y*64 + c0];
  *(bf16x8*)&dst[0] = *(bf16x8*)&o[0];
  *(bf16x8*)&dst[8] = *(bf16x8*)&o[8];
}

// bf16 V both branches -> Vt[128 heads][d][token]
__global__ __launch_bounds__(256)
void vtrans_both(const u16* __restrict__ QKVp, u16* __restrict__ Vt)
{
  __shared__ u16 t[64][72];
  int z = blockIdx.z;
  int br = z >> 6, zz = z & 63, b = zz >> 4, h = zz & 15;
  const u16* src = QKVp + (long)br*QKVSZ + (long)b*SEQ*QKVN + h*HDIM + 2*DIM;
  u16* dst = Vt + (long)z*HDIM*SEQ;
  int tid = threadIdx.x, r = tid >> 2, c0 = (tid & 3)*16;
  int tok0 = blockIdx.x*64, d0 = blockIdx.y*64;
  #pragma unroll
  for (int u = 0; u < 16; u += 8) {
    bf16x8 v = *(const bf16x8*)&src[(long)(tok0+r)*QKVN + d0 + c0 + u];
    #pragma unroll
    for (int e = 0; e < 8; e++) t[r][c0+u+e] = (u16)v[e];
  }
  __syncthreads();
  u16 o[16] __attribute__((aligned(16)));
  #pragma unroll
  for (int u = 0; u < 16; u++) o[u] = t[c0+u][r];
  *(bf16x8*)&dst[(long)(d0+r)*SEQ + tok0 + c0]     = *(bf16x8*)&o[0];
  *(bf16x8*)&dst[(long)(d0+r)*SEQ + tok0 + c0 + 8] = *(bf16x8*)&o[8];
}

// ---------------------------------------------------------------------------
// small elementwise kernels
// ---------------------------------------------------------------------------
__global__ __launch_bounds__(256)
void f32_to_bf16(const float* __restrict__ in, u16* __restrict__ o, long n8)
{
  long i = (long)blockIdx.x*256 + threadIdx.x;
  if (i >= n8) return; i *= 8;
  f32x4 a = *(const f32x4*)&in[i], b = *(const f32x4*)&in[i+4];
  u16 w[8] __attribute__((aligned(16)));
  w[0]=f2bf(a.x);w[1]=f2bf(a.y);w[2]=f2bf(a.z);w[3]=f2bf(a.w);
  w[4]=f2bf(b.x);w[5]=f2bf(b.y);w[6]=f2bf(b.z);w[7]=f2bf(b.w);
  *(bf16x8*)&o[i] = *(bf16x8*)w;
}

__global__ __launch_bounds__(256)
void egather(const int* __restrict__ mods, const float* __restrict__ emb, u16* __restrict__ E)
{
  int i = blockIdx.x*256 + threadIdx.x;
  int row = i >> 3, j0 = (i & 7)*8;
  int m = mods[row]; if (m < 1) m = 1;
  const float* s = &emb[(long)m*64 + j0];
  f32x4 a = *(const f32x4*)s, b = *(const f32x4*)(s+4);
  u16 w[8] __attribute__((aligned(16)));
  w[0]=f2bf(a.x);w[1]=f2bf(a.y);w[2]=f2bf(a.z);w[3]=f2bf(a.w);
  w[4]=f2bf(b.x);w[5]=f2bf(b.y);w[6]=f2bf(b.z);w[7]=f2bf(b.w);
  *(bf16x8*)&E[(long)row*64 + j0] = *(bf16x8*)w;
}

__global__ __launch_bounds__(256)
void film_apply(const float* __restrict__ x, const u16* __restrict__ G,
                const u16* __restrict__ B, u16* __restrict__ y)
{
  long i = ((long)blockIdx.x*256 + threadIdx.x)*8;
  f32x4 x0 = *(const f32x4*)&x[i], x1 = *(const f32x4*)&x[i+4];
  bf16x8 g = *(const bf16x8*)&G[i], b = *(const bf16x8*)&B[i];
  float xv[8] = {x0.x,x0.y,x0.z,x0.w,x1.x,x1.y,x1.z,x1.w};
  u16 w[8] __attribute__((aligned(16)));
  #pragma unroll
  for (int e = 0; e < 8; e++)
    w[e] = f2bf((1.0f + bf2f((u16)g[e]))*xv[e] + bf2f((u16)b[e]));
  *(bf16x8*)&y[i] = *(bf16x8*)w;
}

__global__ __launch_bounds__(256)
void pack_bias(float* __restrict__ dst,
               const float* q_a, const float* k_a, const float* v_a,
               const float* q_e, const float* k_e, const float* v_e,
               const float* o_a, const float* o_e,
               const float* fg, const float* fb)
{
  int i = blockIdx.x*256 + threadIdx.x;
  if (i < 12288) {
    int br = i/6144, r = i - br*6144, sel = r >> 11, o = r & 2047;
    const float* s = br ? (sel==0?q_e:sel==1?k_e:v_e)
                        : (sel==0?q_a:sel==1?k_a:v_a);
    dst[i] = s[o];
  } else if (i < 16384) {
    int r = i - 12288; dst[i] = (r>>11) ? o_e[r&2047] : o_a[r&2047];
  } else {
    int r = i - 16384; dst[i] = (r>>11) ? fb[r&2047] : fg[r&2047];
  }
}

// ---------------------------------------------------------------------------
// LayerNorms
// ---------------------------------------------------------------------------
__global__ __launch_bounds__(256)
void ln_gate(const float* __restrict__ x, const u16* __restrict__ z0,
             const u16* __restrict__ z1, const float* __restrict__ ga,
             const float* __restrict__ g, const float* __restrict__ b,
             u16* __restrict__ h)
{
  __shared__ float red[8];
  long base = (long)blockIdx.x*DIM;
  int t8 = threadIdx.x*8, lane = threadIdx.x & 63, wid = threadIdx.x >> 6;
  float a0 = ga[0], a1 = ga[1];
  float mm = fmaxf(a0,a1), e0 = __expf(a0-mm), e1 = __expf(a1-mm);
  float w0 = e0/(e0+e1), w1 = e1/(e0+e1);
  f32x4 x0 = *(const f32x4*)&x[base+t8], x1 = *(const f32x4*)&x[base+t8+4];
  bf16x8 zi = *(const bf16x8*)&z0[base+t8], ze = *(const bf16x8*)&z1[base+t8];
  float xv[8] = {x0.x,x0.y,x0.z,x0.w,x1.x,x1.y,x1.z,x1.w};
  float v[8]; float s = 0.0f;
  #pragma unroll
  for (int j = 0; j < 8; j++) {
    v[j] = xv[j] + w0*bf2f((u16)zi[j]) + w1*bf2f((u16)ze[j]);
    s += v[j];
  }
  for (int o = 32; o; o >>= 1) s += __shfl_xor(s, o);
  if (lane == 0) red[wid] = s;
  __syncthreads();
  float mean = (red[0]+red[1]+red[2]+red[3])*(1.0f/DIM);
  float q = 0.0f;
  #pragma unroll
  for (int j = 0; j < 8; j++) { float d = v[j]-mean; q += d*d; }
  for (int o = 32; o; o >>= 1) q += __shfl_xor(q, o);
  if (lane == 0) red[4+wid] = q;
  __syncthreads();
  float inv = rsqrtf((red[4]+red[5]+red[6]+red[7])*(1.0f/DIM) + 1e-5f);
  f32x4 g0 = *(const f32x4*)&g[t8], g1 = *(const f32x4*)&g[t8+4];
  f32x4 b0 = *(const f32x4*)&b[t8], b1 = *(const f32x4*)&b[t8+4];
  float gv[8] = {g0.x,g0.y,g0.z,g0.w,g1.x,g1.y,g1.z,g1.w};
  float bv[8] = {b0.x,b0.y,b0.z,b0.w,b1.x,b1.y,b1.z,b1.w};
  u16 w[8] __attribute__((aligned(16)));
  #pragma unroll
  for (int j = 0; j < 8; j++) w[j] = f2bf((v[j]-mean)*inv*gv[j] + bv[j]);
  *(bf16x8*)&h[base+t8] = *(bf16x8*)w;
}

__global__ __launch_bounds__(256)
void ln_res(const u16* __restrict__ hin, const u16* __restrict__ y,
            const float* __restrict__ g, const float* __restrict__ b,
            float* __restrict__ out)
{
  __shared__ float red[8];
  long base = (long)blockIdx.x*DIM;
  int t8 = threadIdx.x*8, lane = threadIdx.x & 63, wid = threadIdx.x >> 6;
  bf16x8 hv = *(const bf16x8*)&hin[base+t8], yv = *(const bf16x8*)&y[base+t8];
  float v[8]; float s = 0.0f;
  #pragma unroll
  for (int j = 0; j < 8; j++) { v[j] = bf2f((u16)hv[j]) + bf2f((u16)yv[j]); s += v[j]; }
  for (int o = 32; o; o >>= 1) s += __shfl_xor(s, o);
  if (lane == 0) red[wid] = s;
  __syncthreads();
  float mean = (red[0]+red[1]+red[2]+red[3])*(1.0f/DIM);
  float q = 0.0f;
  #pragma unroll
  for (int j = 0; j < 8; j++) { float d = v[j]-mean; q += d*d; }
  for (int o = 32; o; o >>= 1) q += __shfl_xor(q, o);
  if (lane == 0) red[4+wid] = q;
  __syncthreads();
  float inv = rsqrtf((red[4]+red[5]+red[6]+red[7])*(1.0f/DIM) + 1e-5f);
  f32x4 g0 = *(const f32x4*)&g[t8], g1 = *(const f32x4*)&g[t8+4];
  f32x4 b0 = *(const f32x4*)&b[t8], b1 = *(const f32x4*)&b[t8+4];
  float gv[8] = {g0.x,g0.y,g0.z,g0.w,g1.x,g1.y,g1.z,g1.w};
  float bv[8] = {b0.x,b0.y,b0.z,b0.w,b1.x,b1.y,b1.z,b1.w};
  f32x4 o0, o1;
  #pragma unroll
  for (int j = 0; j < 4; j++) o0[j] = (v[j]-mean)*inv*gv[j] + bv[j];
  #pragma unroll
  for (int j = 0; j < 4; j++) o1[j] = (v[4+j]-mean)*inv*gv[4+j] + bv[4+j];
  *(f32x4*)&out[base+t8] = o0;
  *(f32x4*)&out[base+t8+4] = o1;
}

// ---------------------------------------------------------------------------
static void G4(hipStream_t st, const u16* A,int lda,long sAo,long sAi,
               const u16* B,int ldb,long sBo,long sBi,
               void* C,int ldc,long sCo,long sCi,int outbf,
               const float* bias,long sbias,int M,int N,int K,int batch,int hdiv,int relu)
{
  gemm4<<<dim3(N/128,M/128,batch),dim3(256),0,st>>>(
      A,lda,sAo,sAi,B,ldb,sBo,sBi,C,ldc,sCo,sCi,outbf,bias,sbias,K,hdiv,relu);
}
static void G8P(hipStream_t st, const u16* A,int lda,long sAo,
                const u16* B,int ldb,long sBo,
                u16* C,int ldc,long sCo,
                const float* bias,long sbias,int M,int N,int K,int batch,int relu)
{
  gemm8p<<<dim3(N/256,M/256,batch),dim3(512),0,st>>>(
      A,lda,sAo,B,ldb,sBo,C,ldc,sCo,bias,sbias,K,relu);
}

extern "C" void kernel_launch(void* const* d_in, const int* in_sizes, int n_in,
                              void* d_out, int out_size, void* d_ws, size_t ws_size,
                              hipStream_t stream)
{
  const float* x          = (const float*)d_in[0];
  const float* mask_intra = (const float*)d_in[1];
  const float* mask_inter = (const float*)d_in[2];
  const int*   mods       = (const int*)  d_in[3];
  const float* film_emb   = (const float*)d_in[4];
  const float* film_gw    = (const float*)d_in[5];
  const float* film_gb    = (const float*)d_in[6];
  const float* film_bw    = (const float*)d_in[7];
  const float* film_bb    = (const float*)d_in[8];
  const float* gate_alpha = (const float*)d_in[9];
  const float* ln1_g = (const float*)d_in[10];
  const float* ln1_b = (const float*)d_in[11];
  const float* ln2_g = (const float*)d_in[12];
  const float* ln2_b = (const float*)d_in[13];
  const float* ffn_w1 = (const float*)d_in[14];
  const float* ffn_b1 = (const float*)d_in[15];
  const float* ffn_w2 = (const float*)d_in[16];
  const float* ffn_b2 = (const float*)d_in[17];
  const float* wq_a = (const float*)d_in[18]; const float* bq_a = (const float*)d_in[19];
  const float* wk_a = (const float*)d_in[20]; const float* bk_a = (const float*)d_in[21];
  const float* wv_a = (const float*)d_in[22]; const float* bv_a = (const float*)d_in[23];
  const float* wo_a = (const float*)d_in[24]; const float* bo_a = (const float*)d_in[25];
  const float* wq_e = (const float*)d_in[26]; const float* bq_e = (const float*)d_in[27];
  const float* wk_e = (const float*)d_in[28]; const float* bk_e = (const float*)d_in[29];
  const float* wv_e = (const float*)d_in[30]; const float* bv_e = (const float*)d_in[31];
  const float* wo_e = (const float*)d_in[32]; const float* bo_e = (const float*)d_in[33];

  // ---- lifetime-overlapped arena (audited R13) ----
  char* ws = (char*)d_ws;
  u16*   ybf  = (u16*)(ws);                      // 0..8Mi  y_intra (dead after QKV)
  u16*   xbf  = (u16*)(ws + (8L<<20));           // 8..16Mi x bf16 (dead after QKV)
  u16*   AO   = (u16*)(ws);                      // 0..16Mi attn out (PV -> out-proj)
  u16*   QKV  = (u16*)(ws + (16L<<20));          // 16..64Mi (dead after vtrans/qkprobs)
  u16*   Gf   = QKV;
  u16*   Bfm  = QKV + DSZ;
  u16*   zbuf = (u16*)(ws + (16L<<20));          // 16..32 (out-proj out; QKV dead)
  u16*   hbf  = (u16*)(ws + (32L<<20));          // 32..40
  u16*   Wst  = (u16*)(ws + (64L<<20));          // 64..96 weight staging
  u16*   Pall = (u16*)(ws + (96L<<20));          // 96..160 probs both branches
  u16*   mid  = (u16*)(ws + (96L<<20));          // 96..128 ffn mid (P dead by FFN)
  float* Pf2  = (float*)(ws + (128L<<20));       // 128..160 ffn2 partials (P dead)
  u16*   f2o  = (u16*)(ws + (16L<<20));          // 16..24 ffn2 out (zbuf dead after ln_gate)
  u16*   Vt   = (u16*)(ws + (160L<<20));         // 160..176 V^T both branches
  u16*   Ebuf = (u16*)(ws + (160L<<20));         //   (pre-Vt)
  u16*   Wfm  = (u16*)(ws + (161L<<20));         //   (pre-Vt)
  float* bpk  = (float*)(ws + (176L<<20));       // packed biases (80 KiB)

  // ---- conversions + packing ----
  f32_to_bf16<<<2048,256,0,stream>>>(x, xbf, DSZ/8);
  egather<<<64,256,0,stream>>>(mods, film_emb, Ebuf);
  {
    P6 pf; pf.p[0]=film_gw; pf.p[1]=film_bw;
    pf.p[2]=film_gw; pf.p[3]=film_gw; pf.p[4]=film_gw; pf.p[5]=film_gw;
    wtrans6<<<dim3(32,1,2),256,0,stream>>>(pf, DIM, Wfm, (long)DIM*64, 64);
  }
  pack_bias<<<80,256,0,stream>>>(bpk, bq_a,bk_a,bv_a, bq_e,bk_e,bv_e, bo_a,bo_e, film_gb,film_bb);

  // ---- FiLM: [G|B] = E @ [gw|bw] + bias (gemm4, z=2, K=64) ----
  G4(stream, Ebuf,64,0,0, Wfm,64,(long)DIM*64,0, Gf,DIM,DSZ,0,1,
     bpk+16384,2048, BTOK,DIM,64, 2,1, 0);
  film_apply<<<2048,256,0,stream>>>(x, Gf, Bfm, ybf);

  // ---- QKV both branches (gemm8p, z=2) ----
  {
    P6 pq; pq.p[0]=wq_a; pq.p[1]=wk_a; pq.p[2]=wv_a;
    pq.p[3]=wq_e; pq.p[4]=wk_e; pq.p[5]=wv_e;
    wtrans6<<<dim3(32,32,6),256,0,stream>>>(pq, DIM, Wst, (long)DIM*DIM, DIM);
  }
  G8P(stream, ybf,DIM,DSZ, Wst,DIM,(long)QKVN*DIM, QKV,QKVN,QKVSZ,
      bpk,QKVN, BTOK,QKVN,DIM, 2, 0);

  // ---- attention: vtrans(both) ; qkprobs(both, BM=32) ; PV(both, gemm4) ----
  vtrans_both<<<dim3(8,2,128),256,0,stream>>>(QKV, Vt);
  qkprobs_both<<<dim3(128,16),dim3(256),0,stream>>>(QKV, mask_intra, mask_inter, Pall);
  G4(stream, Pall,SEQ,(long)16*SEQ*SEQ,(long)SEQ*SEQ,
     Vt,SEQ,(long)16*HDIM*SEQ,(long)HDIM*SEQ,
     AO,DIM,(long)SEQ*DIM,HDIM,1, nullptr,0,
     SEQ,HDIM,SEQ, 128,16, 0);

  // ---- out-proj (gemm4, z=2) -> z bf16 ----
  {
    P6 po; po.p[0]=wo_a; po.p[1]=wo_e;
    po.p[2]=wo_a; po.p[3]=wo_a; po.p[4]=wo_a; po.p[5]=wo_a;
    wtrans6<<<dim3(32,32,2),256,0,stream>>>(po, DIM, Wst, (long)DIM*DIM, DIM);
  }
  G4(stream, AO,DIM,DSZ,0, Wst,DIM,(long)DIM*DIM,0, zbuf,DIM,DSZ,0,1,
     bpk+12288,DIM, BTOK,DIM,DIM, 2,1, 0);

  // ---- gate + LN1 ----
  ln_gate<<<2048,256,0,stream>>>(x, zbuf, zbuf+DSZ, gate_alpha, ln1_g, ln1_b, hbf);

  // ---- FFN ----
  wtrans<<<dim3(128,32),256,0,stream>>>(ffn_w1, FFDIM, Wst, DIM);
  G8P(stream, hbf,DIM,0, Wst,DIM,0, mid,FFDIM,0,
      ffn_b1,0, BTOK,FFDIM,DIM, 1, 1);                                     // relu
  wtrans<<<dim3(32,128),256,0,stream>>>(ffn_w2, DIM, Wst, FFDIM);
  // FFN2 split-K x2 -> grid (16,16,2)=512 blocks
  G4(stream, mid,FFDIM,4096,0, Wst,FFDIM,4096,0, Pf2,DIM,DSZ,0,0,
     nullptr,0, BTOK,DIM,4096, 2,1, 0);
  redk<<<2048,256,0,stream>>>(Pf2, 2, ffn_b2, f2o);

  // ---- LN2 -> out ----
  ln_res<<<2048,256,0,stream>>>(hbf, f2o, ln2_g, ln2_b, (float*)d_out);
}

// Round 20
// 584.317 us; speedup vs baseline: 1.0300x; 1.0300x over previous
//
#include <hip/hip_runtime.h>
#include <hip/hip_bf16.h>

typedef float f32x4 __attribute__((ext_vector_type(4)));
typedef short bf16x8 __attribute__((ext_vector_type(8)));
typedef unsigned short u16;

#define SEQ    512
#define DIM    2048
#define NHEAD  16
#define HDIM   128
#define BATCH  4
#define BTOK   2048
#define FFDIM  8192
#define DSZ    ((long)BTOK*DIM)       // 4,194,304 elements (2^22)
#define QKVN   (3*DIM)                // 6144
#define QKVSZ  ((long)BTOK*QKVN)
#define ISS    0.08838834764831845f   // 1/sqrt(128)

__device__ __forceinline__ u16 f2bf(float f){
  union{float fv;unsigned u;}c;c.fv=f;
  unsigned r=c.u+0x7FFFu+((c.u>>16)&1u); return (u16)(r>>16);
}
__device__ __forceinline__ float bf2f(u16 v){
  union{unsigned u;float f;}c;c.u=((unsigned)v)<<16;return c.f;
}
__device__ __forceinline__ float pow103(float t){
  return __builtin_amdgcn_exp2f(__builtin_amdgcn_logf(t)*(10.0f/3.0f));
}

// async global->LDS, 16B per lane, LDS dest = wave-uniform base + lane*16
#define GLD16(g,l) __builtin_amdgcn_global_load_lds( \
    (const __attribute__((address_space(1))) unsigned int*)(g), \
    (__attribute__((address_space(3))) unsigned int*)(l), 16, 0, 0)

#define MF(a,b,c) __builtin_amdgcn_mfma_f32_16x16x32_bf16(a,b,c,0,0,0)
#define VMW(n) do{ asm volatile("s_waitcnt vmcnt(" #n ")" ::: "memory"); \
                   __builtin_amdgcn_sched_barrier(0); }while(0)
#define LGKM0() do{ asm volatile("s_waitcnt lgkmcnt(0)" ::: "memory"); \
                    __builtin_amdgcn_sched_barrier(0); }while(0)
#define BARR() do{ asm volatile("" ::: "memory"); __builtin_amdgcn_s_barrier(); \
                   asm volatile("" ::: "memory"); }while(0)

// ---------------------------------------------------------------------------
// gemm4w: 128x256 block, 4 waves (each 128x64, 8x4 acc), BK=32, 3-deep
// pipeline, 72 KiB LDS -> 2 blocks/CU. Verified R12/R18 (35.6% MfmaUtil).
// ---------------------------------------------------------------------------
__global__ __launch_bounds__(256, 2)
void gemm4w(const u16* __restrict__ A, int lda, long sAo, long sAi,
            const u16* __restrict__ B, int ldb, long sBo, long sBi,
            u16* __restrict__ C, int ldc, long sCo,
            const float* __restrict__ bias, long sbias,
            int K, int hdiv, int relu)
{
  __shared__ __align__(16) u16 sm[36864];     // 72 KiB = 3 x (8K A + 16K B)
  char* smb = (char*)sm;

  int gx = gridDim.x, gy = gridDim.y;
  int nwg = gx*gy*gridDim.z;
  int flat = (blockIdx.z*gy + blockIdx.y)*gx + blockIdx.x;
  int cpx = nwg >> 3; flat = (flat & 7)*cpx + (flat >> 3);
  int by = flat % gy; int tq = flat / gy; int bx = tq % gx; int bz = tq / gx;

  int zo = bz / hdiv, zi = bz - zo*hdiv;
  const u16* Ab = A + (long)zo*sAo + (long)zi*sAi;
  const u16* Bb = B + (long)zo*sBo + (long)zi*sBi;
  int m0 = by*128, n0 = bx*256;

  int tid = threadIdx.x, lane = tid & 63, w = tid >> 6;
  int lr = lane & 15, lg = lane >> 4;
  int rl = lane >> 2, cbyte = (lane & 3)*16;

  int sRA[2], sCA[2];
  #pragma unroll
  for (int q = 0; q < 2; q++) {
    int r = (2*w+q)*16 + rl;
    sRA[q] = r ^ ((r>>2)&1);
    sCA[q] = (cbyte ^ ((((r>>2)^r)&1)<<4) ^ (((r>>1)&1)<<5)) >> 1;
  }
  int sRB[4], sCB[4];
  #pragma unroll
  for (int q = 0; q < 4; q++) {
    int r = (4*w+q)*16 + rl;
    sRB[q] = r ^ ((r>>2)&1);
    sCB[q] = (cbyte ^ ((((r>>2)^r)&1)<<4) ^ (((r>>1)&1)<<5)) >> 1;
  }

  int aoff = (lr*64 + lg*16) ^ ((lane&7)<<4);
  int boff = w*4096 + ((lr*64 + lg*16) ^ ((lane&7)<<4));

  f32x4 acc[8][4] = {};
  int NT = K >> 5;

  auto STG = [&](int buf, int kt) {
    int kcol = kt*32;
    char* base = smb + buf*24576;
    #pragma unroll
    for (int q = 0; q < 2; q++)
      GLD16(Ab + (long)(m0 + sRA[q])*lda + kcol + sCA[q], base + (2*w+q)*1024);
    #pragma unroll
    for (int q = 0; q < 4; q++)
      GLD16(Bb + (long)(n0 + sRB[q])*ldb + kcol + sCB[q], base + 8192 + (4*w+q)*1024);
  };

  STG(0,0);
  if (NT > 1) STG(1,1);

  int buf = 0;
  for (int t = 0; t < NT; t++) {
    char* Ax = smb + buf*24576;
    char* Bx = Ax + 8192;

    if (t+2 < NT) {
      int nb = buf + 2; if (nb >= 3) nb -= 3;
      STG(nb, t+2);
      VMW(12);
    } else if (t+1 < NT) { VMW(6); }
    else                 { VMW(0); }
    BARR();

    bf16x8 af[8], bv[4];
    #pragma unroll
    for (int i = 0; i < 8; i++) af[i] = *(const bf16x8*)(Ax + aoff + i*1024);
    #pragma unroll
    for (int j = 0; j < 4; j++) bv[j] = *(const bf16x8*)(Bx + boff + j*1024);
    LGKM0();
    __builtin_amdgcn_s_setprio(1);
    #pragma unroll
    for (int i = 0; i < 8; i++) {
      acc[i][0] = MF(af[i], bv[0], acc[i][0]);
      acc[i][1] = MF(af[i], bv[1], acc[i][1]);
      acc[i][2] = MF(af[i], bv[2], acc[i][2]);
      acc[i][3] = MF(af[i], bv[3], acc[i][3]);
    }
    __builtin_amdgcn_s_setprio(0);
    BARR();
    buf++; if (buf == 3) buf = 0;
  }

  u16* Cb = C + (long)bz*sCo;
  #pragma unroll
  for (int j = 0; j < 4; j++) {
    int col = n0 + w*64 + j*16 + lr;
    float bv2 = bias ? bias[zo*sbias + col] : 0.0f;
    #pragma unroll
    for (int i = 0; i < 8; i++) {
      #pragma unroll
      for (int e = 0; e < 4; e++) {
        int row = m0 + i*16 + lg*4 + e;
        float v = acc[i][j][e] + bv2;
        if (relu) v = fmaxf(v, 0.0f);
        Cb[(long)row*ldc + col] = f2bf(v);
      }
    }
  }
}

// ---------------------------------------------------------------------------
// gemm4: 128x128 tile, BK=32, 4 waves, 3-deep pipeline, 48 KiB LDS
// (3 blocks/CU). C offset = zo*sCo + zi*sCi (supports per-head PV output).
// ---------------------------------------------------------------------------
__global__ __launch_bounds__(256, 3)
void gemm4(const u16* __restrict__ A, int lda, long sAo, long sAi,
           const u16* __restrict__ B, int ldb, long sBo, long sBi,
           void* __restrict__ C, int ldc, long sCo, long sCi, int outbf,
           const float* __restrict__ bias, long sbias,
           int K, int hdiv, int relu)
{
  __shared__ __align__(16) u16 sm[24576];     // 48 KiB
  char* smb = (char*)sm;

  int gx = gridDim.x, gy = gridDim.y;
  int nwg = gx*gy*gridDim.z;
  int flat = (blockIdx.z*gy + blockIdx.y)*gx + blockIdx.x;
  int cpx = nwg >> 3; flat = (flat & 7)*cpx + (flat >> 3);
  int by = flat % gy; int tq = flat / gy; int bx = tq % gx; int bz = tq / gx;

  int zo = bz / hdiv, zi = bz - zo*hdiv;
  const u16* Ab = A + (long)zo*sAo + (long)zi*sAi;
  const u16* Bb = B + (long)zo*sBo + (long)zi*sBi;
  int m0 = by*128, n0 = bx*128;

  int tid = threadIdx.x, lane = tid & 63, w = tid >> 6;
  int wrow = (w>>1)*64, wn = (w&1)*64;
  int lr = lane & 15, lg = lane >> 4;

  int stR[2], stC[2], ldsch[2];
  #pragma unroll
  for (int q = 0; q < 2; q++) {
    int chunk = q*4 + w;
    int r = chunk*16 + (lane>>2);
    int c = (lane&3)*16;
    int Rz = r ^ ((r>>2)&1);
    int Cz = c ^ ((((r>>2)^r)&1)<<4) ^ (((r>>1)&1)<<5);
    stR[q] = Rz; stC[q] = Cz>>1;
    ldsch[q] = chunk*1024;
  }

  int aoff = ((wrow + lr)*64 + lg*16) ^ ((lane&7)<<4);
  int boff = ((wn  + lr)*64 + lg*16) ^ ((lane&7)<<4);

  f32x4 acc[4][4] = {};
  int NT = K >> 5;

  auto STG = [&](int buf, int op, int kt) {
    const u16* gp = op ? Bb : Ab;
    int ld   = op ? ldb : lda;
    int base = op ? n0 : m0;
    int kcol = kt*32;
    #pragma unroll
    for (int q = 0; q < 2; q++) {
      const u16* src = gp + (long)(base + stR[q])*ld + kcol + stC[q];
      char* dst = smb + buf*16384 + op*8192 + ldsch[q];
      GLD16(src, dst);
    }
  };

  STG(0,0,0); STG(0,1,0);
  if (NT > 1) { STG(1,0,1); STG(1,1,1); }

  int buf = 0;
  for (int t = 0; t < NT; t++) {
    char* Ax = smb + buf*16384;
    char* Bx = smb + buf*16384 + 8192;

    if (t+2 < NT) {
      int nb = buf + 2; if (nb >= 3) nb -= 3;
      STG(nb,0,t+2); STG(nb,1,t+2);
      VMW(8);
    } else if (t+1 < NT) { VMW(4); }
    else                 { VMW(0); }
    BARR();

    bf16x8 af[4], bv[4];
    #pragma unroll
    for (int i = 0; i < 4; i++) af[i] = *(const bf16x8*)(Ax + aoff + i*1024);
    #pragma unroll
    for (int j = 0; j < 4; j++) bv[j] = *(const bf16x8*)(Bx + boff + j*1024);
    LGKM0();
    __builtin_amdgcn_s_setprio(1);
    #pragma unroll
    for (int i = 0; i < 4; i++) {
      acc[i][0] = MF(af[i], bv[0], acc[i][0]);
      acc[i][1] = MF(af[i], bv[1], acc[i][1]);
      acc[i][2] = MF(af[i], bv[2], acc[i][2]);
      acc[i][3] = MF(af[i], bv[3], acc[i][3]);
    }
    __builtin_amdgcn_s_setprio(0);
    BARR();
    buf++; if (buf == 3) buf = 0;
  }

  long coff = (long)zo*sCo + (long)zi*sCi;
  if (outbf) {
    u16* Cb = (u16*)C + coff;
    #pragma unroll
    for (int j = 0; j < 4; j++) {
      int col = n0 + wn + j*16 + lr;
      float bv2 = bias ? bias[zo*sbias + col] : 0.0f;
      #pragma unroll
      for (int i = 0; i < 4; i++) {
        #pragma unroll
        for (int e = 0; e < 4; e++) {
          int row = m0 + wrow + i*16 + lg*4 + e;
          float v = acc[i][j][e] + bv2;
          if (relu) v = fmaxf(v, 0.0f);
          Cb[(long)row*ldc + col] = f2bf(v);
        }
      }
    }
  } else {
    float* Cb = (float*)C + coff;
    #pragma unroll
    for (int j = 0; j < 4; j++) {
      int col = n0 + wn + j*16 + lr;
      #pragma unroll
      for (int i = 0; i < 4; i++) {
        #pragma unroll
        for (int e = 0; e < 4; e++) {
          int row = m0 + wrow + i*16 + lg*4 + e;
          Cb[(long)row*ldc + col] = acc[i][j][e];
        }
      }
    }
  }
}

// ---------------------------------------------------------------------------
// qkprobs_both: grid (128, 16): x = br*64+head, y = q-tile (BM=32).
// 40KB LDS (A 8K + K 32K single-buffered), launch_bounds(256,2): compiler
// settles ~116 VGPR, zero spill (R18: WRITE = 64MB exactly). acc[2][8] =
// 64 VGPR score tile fits in registers. Solver: 5 bisect + 3 monotone Newton.
// ---------------------------------------------------------------------------
__global__ __launch_bounds__(256, 2)
void qkprobs_both(const u16* __restrict__ QKVp,
                  const float* __restrict__ maskI, const float* __restrict__ maskE,
                  u16* __restrict__ Pall)
{
  __shared__ __align__(16) u16 sm[20480];      // 40 KiB: A 8K + K 32K
  char* smb = (char*)sm;

  int z2 = blockIdx.x;
  int m0 = blockIdx.y*32;
  int br = z2 >> 6, z = z2 & 63;
  int b  = z >> 4, h = z & 15;
  const float* maskp = br ? maskE : maskI;
  const u16* Qb = QKVp + (long)br*QKVSZ + (long)b*SEQ*QKVN + h*HDIM;
  const u16* Kb = Qb + DIM;
  u16* P = Pall + (long)br*64*SEQ*SEQ;

  int tid = threadIdx.x, lane = tid & 63, w = tid >> 6;
  int lr = lane & 15, lg = lane >> 4;
  int wn = w*128;

  int rl = lane >> 2;
  int cb = (lane & 3)*16;

  int aoff = (lr*64 + lg*16) ^ ((lane&7)<<4);
  int boff = ((wn + lr)*64 + lg*16) ^ ((lane&7)<<4);

  auto stgA = [&](int kt) {
    int r = (w&1)*16 + rl;
    int Rz = r ^ ((r>>2)&1);
    int Cz = cb ^ ((((r>>2)^r)&1)<<4) ^ (((r>>1)&1)<<5);
    GLD16(Qb + (long)(m0+Rz)*QKVN + kt*32 + (Cz>>1), smb + kt*2048 + (w&1)*1024);
  };
  auto stgB = [&](int kt) {
    #pragma unroll
    for (int q = 0; q < 8; q++) {
      int chunk = q*4 + w;
      int r = chunk*16 + rl;
      int Rz = r ^ ((r>>2)&1);
      int Cz = cb ^ ((((r>>2)^r)&1)<<4) ^ (((r>>1)&1)<<5);
      GLD16(Kb + (long)Rz*QKVN + kt*32 + (Cz>>1),
            smb + 8192 + chunk*1024);
    }
  };

  f32x4 acc[2][8] = {};                        // 64 VGPRs

  stgA(0); stgA(1); stgA(2); stgA(3);
  stgB(0);

  #pragma unroll
  for (int kt = 0; kt < 4; kt++) {
    VMW(0);
    BARR();
    char* Bx = smb + 8192;
    bf16x8 af[2], bv[8];
    #pragma unroll
    for (int i = 0; i < 2; i++) af[i] = *(const bf16x8*)(smb + kt*2048 + aoff + i*1024);
    #pragma unroll
    for (int j = 0; j < 8; j++) bv[j] = *(const bf16x8*)(Bx + boff + j*1024);
    LGKM0();
    BARR();
    if (kt < 3) stgB(kt+1);
    __builtin_amdgcn_s_setprio(1);
    #pragma unroll
    for (int i = 0; i < 2; i++)
      #pragma unroll
      for (int j = 0; j < 8; j++)
        acc[i][j] = MF(af[i], bv[j], acc[i][j]);
    __builtin_amdgcn_s_setprio(0);
  }

  float* redA = (float*)smb;
  float* redB = (float*)(smb + 512);

  float rmax[8];
  #pragma unroll
  for (int s = 0; s < 8; s++) rmax[s] = -3.4e38f;
  #pragma unroll
  for (int i = 0; i < 2; i++) {
    #pragma unroll
    for (int e = 0; e < 4; e++) {
      int row = i*16 + lg*4 + e;
      const float* mp = maskp + (long)(m0+row)*SEQ + wn + lr;
      #pragma unroll
      for (int j = 0; j < 8; j++) {
        float v = acc[i][j][e]*ISS + mp[j*16];
        acc[i][j][e] = v;
        rmax[i*4+e] = fmaxf(rmax[i*4+e], v);
      }
    }
  }
  #pragma unroll
  for (int s = 0; s < 8; s++)
    #pragma unroll
    for (int o = 1; o < 16; o <<= 1) rmax[s] = fmaxf(rmax[s], __shfl_xor(rmax[s], o));
  if (lr == 0) {
    #pragma unroll
    for (int i = 0; i < 2; i++)
      #pragma unroll
      for (int e = 0; e < 4; e++) redA[w*32 + i*16 + lg*4 + e] = rmax[i*4+e];
  }
  BARR();
  #pragma unroll
  for (int i = 0; i < 2; i++)
    #pragma unroll
    for (int e = 0; e < 4; e++) {
      int row = i*16 + lg*4 + e;
      rmax[i*4+e] = fmaxf(fmaxf(redA[row], redA[32+row]),
                          fmaxf(redA[64+row], redA[96+row]));
    }
  BARR();

  float inv[8];

  if (br) {
    #pragma unroll
    for (int i = 0; i < 2; i++)
      #pragma unroll
      for (int j = 0; j < 8; j++)
        #pragma unroll
        for (int e = 0; e < 4; e++)
          acc[i][j][e] = (acc[i][j][e] - rmax[i*4+e])*0.3f;

    float lo[8];
    #pragma unroll
    for (int s = 0; s < 8; s++) lo[s] = -1.0f;    // s(-1) >= 1
    float half = 0.5f;

    #pragma unroll 1
    for (int it = 0; it < 5; it++) {              // bisection, lo-only
      float ps[8];
      #pragma unroll
      for (int s = 0; s < 8; s++) ps[s] = 0.0f;
      #pragma unroll
      for (int i = 0; i < 2; i++)
        #pragma unroll
        for (int e = 0; e < 4; e++) {
          float mid = lo[i*4+e] + half;
          #pragma unroll
          for (int j = 0; j < 8; j++) {
            float t = acc[i][j][e] - mid;
            if (t > 0.0f) ps[i*4+e] += pow103(t);
          }
        }
      #pragma unroll
      for (int s = 0; s < 8; s++)
        #pragma unroll
        for (int o = 1; o < 16; o <<= 1) ps[s] += __shfl_xor(ps[s], o);
      if (lr == 0) {
        #pragma unroll
        for (int i = 0; i < 2; i++)
          #pragma unroll
          for (int e = 0; e < 4; e++) redA[w*32 + i*16 + lg*4 + e] = ps[i*4+e];
      }
      BARR();
      #pragma unroll
      for (int i = 0; i < 2; i++)
        #pragma unroll
        for (int e = 0; e < 4; e++) {
          int row = i*16 + lg*4 + e, s = i*4+e;
          float tot = redA[row] + redA[32+row] + redA[64+row] + redA[96+row];
          if (tot > 1.0f) lo[s] += half;          // keep s(lo) >= 1
        }
      BARR();
      half *= 0.5f;
    }

    #pragma unroll 1
    for (int it = 0; it < 3; it++) {              // pure Newton (monotone)
      float ps[8], pd[8];
      #pragma unroll
      for (int s = 0; s < 8; s++) { ps[s] = 0.0f; pd[s] = 0.0f; }
      #pragma unroll
      for (int i = 0; i < 2; i++)
        #pragma unroll
        for (int e = 0; e < 4; e++) {
          float tv = lo[i*4+e];
          #pragma unroll
          for (int j = 0; j < 8; j++) {
            float t = acc[i][j][e] - tv;
            if (t > 0.0f) {
              float w7 = __builtin_amdgcn_exp2f(__builtin_amdgcn_logf(t)*(7.0f/3.0f));
              pd[i*4+e] += w7; ps[i*4+e] += w7*t;
            }
          }
        }
      #pragma unroll
      for (int s = 0; s < 8; s++)
        #pragma unroll
        for (int o = 1; o < 16; o <<= 1) {
          ps[s] += __shfl_xor(ps[s], o);
          pd[s] += __shfl_xor(pd[s], o);
        }
      if (lr == 0) {
        #pragma unroll
        for (int i = 0; i < 2; i++)
          #pragma unroll
          for (int e = 0; e < 4; e++) {
            redA[w*32 + i*16 + lg*4 + e] = ps[i*4+e];
            redB[w*32 + i*16 + lg*4 + e] = pd[i*4+e];
          }
      }
      BARR();
      #pragma unroll
      for (int i = 0; i < 2; i++)
        #pragma unroll
        for (int e = 0; e < 4; e++) {
          int row = i*16 + lg*4 + e, s = i*4+e;
          float st = redA[row] + redA[32+row] + redA[64+row] + redA[96+row];
          float dt = redB[row] + redB[32+row] + redB[64+row] + redB[96+row];
          lo[s] += (st - 1.0f) / ((10.0f/3.0f)*dt + 1e-30f);
        }
      BARR();
    }

    float ps[8];
    #pragma unroll
    for (int s = 0; s < 8; s++) ps[s] = 0.0f;
    #pragma unroll
    for (int i = 0; i < 2; i++)
      #pragma unroll
      for (int e = 0; e < 4; e++) {
        float tv = lo[i*4+e];
        #pragma unroll
        for (int j = 0; j < 8; j++) {
          float t = acc[i][j][e] - tv;
          float p = (t > 0.0f) ? pow103(t) : 0.0f;
          acc[i][j][e] = p;
          ps[i*4+e] += p;
        }
      }
    #pragma unroll
    for (int s = 0; s < 8; s++)
      #pragma unroll
      for (int o = 1; o < 16; o <<= 1) ps[s] += __shfl_xor(ps[s], o);
    if (lr == 0) {
      #pragma unroll
      for (int i = 0; i < 2; i++)
        #pragma unroll
        for (int e = 0; e < 4; e++) redA[w*32 + i*16 + lg*4 + e] = ps[i*4+e];
    }
    BARR();
    #pragma unroll
    for (int i = 0; i < 2; i++)
      #pragma unroll
      for (int e = 0; e < 4; e++) {
        int row = i*16 + lg*4 + e;
        inv[i*4+e] = 1.0f/(redA[row] + redA[32+row] + redA[64+row] + redA[96+row] + 1e-12f);
      }
  } else {
    float ps[8];
    #pragma unroll
    for (int s = 0; s < 8; s++) ps[s] = 0.0f;
    #pragma unroll
    for (int i = 0; i < 2; i++)
      #pragma unroll
      for (int e = 0; e < 4; e++) {
        float mx = rmax[i*4+e];
        #pragma unroll
        for (int j = 0; j < 8; j++) {
          float p = __expf(acc[i][j][e] - mx);
          acc[i][j][e] = p;
          ps[i*4+e] += p;
        }
      }
    #pragma unroll
    for (int s = 0; s < 8; s++)
      #pragma unroll
      for (int o = 1; o < 16; o <<= 1) ps[s] += __shfl_xor(ps[s], o);
    if (lr == 0) {
      #pragma unroll
      for (int i = 0; i < 2; i++)
        #pragma unroll
        for (int e = 0; e < 4; e++) redA[w*32 + i*16 + lg*4 + e] = ps[i*4+e];
    }
    BARR();
    #pragma unroll
    for (int i = 0; i < 2; i++)
      #pragma unroll
      for (int e = 0; e < 4; e++) {
        int row = i*16 + lg*4 + e;
        inv[i*4+e] = 1.0f/(redA[row] + redA[32+row] + redA[64+row] + redA[96+row]);
      }
  }

  // ---- LDS repack: [32 rows][512 cols] u16 (32 KB) in dead K region ----
  BARR();
  char* rp = smb + 8192;
  #pragma unroll
  for (int i = 0; i < 2; i++)
    #pragma unroll
    for (int e = 0; e < 4; e++) {
      int r = i*16 + lg*4 + e;
      float sc = inv[i*4+e];
      #pragma unroll
      for (int j = 0; j < 8; j++) {
        int cbyt = (wn + j*16 + lr)*2;
        *(u16*)(rp + r*1024 + (cbyt ^ ((r&7)<<4))) = f2bf(acc[i][j][e]*sc);
      }
    }
  BARR();
  u16* Pb = P + ((long)z*SEQ + m0)*SEQ;
  #pragma unroll
  for (int chunk = 0; chunk < 8; chunk++) {
    int p = chunk*4096 + tid*16;
    int row = p >> 10, cb2 = p & 1023;
    bf16x8 v = *(const bf16x8*)(rp + row*1024 + (cb2 ^ ((row&7)<<4)));
    *(bf16x8*)((char*)Pb + p) = v;
  }
}

// ---------------------------------------------------------------------------
// split-K reduce
// ---------------------------------------------------------------------------
__global__ __launch_bounds__(256)
void redk(const float* __restrict__ Pp, int nk, const float* __restrict__ bias,
          u16* __restrict__ out)
{
  long i = ((long)blockIdx.x*256 + threadIdx.x)*8;
  long z = i >> 22;
  int  n = (int)(i & 2047);
  float v[8] = {};
  for (int k = 0; k < nk; k++) {
    const float* s = Pp + (z*nk + k)*DSZ + (i & (DSZ-1));
    f32x4 aa = *(const f32x4*)s, bb = *(const f32x4*)(s+4);
    v[0]+=aa.x; v[1]+=aa.y; v[2]+=aa.z; v[3]+=aa.w;
    v[4]+=bb.x; v[5]+=bb.y; v[6]+=bb.z; v[7]+=bb.w;
  }
  f32x4 b0 = *(const f32x4*)&bias[z*2048 + n], b1 = *(const f32x4*)&bias[z*2048 + n + 4];
  float bv[8] = {b0.x,b0.y,b0.z,b0.w,b1.x,b1.y,b1.z,b1.w};
  u16 w[8] __attribute__((aligned(16)));
  #pragma unroll
  for (int j = 0; j < 8; j++) w[j] = f2bf(v[j] + bv[j]);
  *(bf16x8*)&out[i] = *(bf16x8*)w;
}

// ---------------------------------------------------------------------------
// fp32 W[k][n] -> bf16 Wt[n][k]; wtrans6 batches up to 6 same-shape sources
// ---------------------------------------------------------------------------
struct P6 { const float* p[6]; };

__global__ __launch_bounds__(256)
void wtrans6(P6 srcs, int ldw, u16* __restrict__ Wt, long dstStride, int ldt)
{
  __shared__ u16 t[64][72];
  const float* W = srcs.p[blockIdx.z];
  u16* Wd = Wt + (long)blockIdx.z*dstStride;
  int tid = threadIdx.x, r = tid >> 2, c0 = (tid & 3)*16;
  long gr = (long)blockIdx.y*64 + r, gc = (long)blockIdx.x*64 + c0;
  #pragma unroll
  for (int u = 0; u < 16; u += 4) {
    f32x4 v = *(const f32x4*)&W[gr*ldw + gc + u];
    t[r][c0+u+0]=f2bf(v.x); t[r][c0+u+1]=f2bf(v.y);
    t[r][c0+u+2]=f2bf(v.z); t[r][c0+u+3]=f2bf(v.w);
  }
  __syncthreads();
  u16 o[16] __attribute__((aligned(16)));
  #pragma unroll
  for (int u = 0; u < 16; u++) o[u] = t[c0+u][r];
  u16* dst = &Wd[(long)(blockIdx.x*64 + r)*ldt + blockIdx.y*64 + c0];
  *(bf16x8*)&dst[0] = *(bf16x8*)&o[0];
  *(bf16x8*)&dst[8] = *(bf16x8*)&o[8];
}

__global__ __launch_bounds__(256)
void wtrans(const float* __restrict__ W, int ldw, u16* __restrict__ Wt, int ldt)
{
  __shared__ u16 t[64][72];
  int tid = threadIdx.x, r = tid >> 2, c0 = (tid & 3)*16;
  long gr = (long)blockIdx.y*64 + r, gc = (long)blockIdx.x*64 + c0;
  #pragma unroll
  for (int u = 0; u < 16; u += 4) {
    f32x4 v = *(const f32x4*)&W[gr*ldw + gc + u];
    t[r][c0+u+0]=f2bf(v.x); t[r][c0+u+1]=f2bf(v.y);
    t[r][c0+u+2]=f2bf(v.z); t[r][c0+u+3]=f2bf(v.w);
  }
  __syncthreads();
  u16 o[16] __attribute__((aligned(16)));
  #pragma unroll
  for (int u = 0; u < 16; u++) o[u] = t[c0+u][r];
  u16* dst = &Wt[(long)(blockIdx.x*64 + r)*ldt + blockIdx.y*64 + c0];
  *(bf16x8*)&dst[0] = *(bf16x8*)&o[0];
  *(bf16x8*)&dst[8] = *(bf16x8*)&o[8];
}

// bf16 V both branches -> Vt[128 heads][d][token]
__global__ __launch_bounds__(256)
void vtrans_both(const u16* __restrict__ QKVp, u16* __restrict__ Vt)
{
  __shared__ u16 t[64][72];
  int z = blockIdx.z;                          // 0..127
  int br = z >> 6, zz = z & 63, b = zz >> 4, h = zz & 15;
  const u16* src = QKVp + (long)br*QKVSZ + (long)b*SEQ*QKVN + h*HDIM + 2*DIM;
  u16* dst = Vt + (long)z*HDIM*SEQ;
  int tid = threadIdx.x, r = tid >> 2, c0 = (tid & 3)*16;
  int tok0 = blockIdx.x*64, d0 = blockIdx.y*64;
  #pragma unroll
  for (int u = 0; u < 16; u += 8) {
    bf16x8 v = *(const bf16x8*)&src[(long)(tok0+r)*QKVN + d0 + c0 + u];
    #pragma unroll
    for (int e = 0; e < 8; e++) t[r][c0+u+e] = (u16)v[e];
  }
  __syncthreads();
  u16 o[16] __attribute__((aligned(16)));
  #pragma unroll
  for (int u = 0; u < 16; u++) o[u] = t[c0+u][r];
  *(bf16x8*)&dst[(long)(d0+r)*SEQ + tok0 + c0]     = *(bf16x8*)&o[0];
  *(bf16x8*)&dst[(long)(d0+r)*SEQ + tok0 + c0 + 8] = *(bf16x8*)&o[8];
}

// ---------------------------------------------------------------------------
// small elementwise kernels
// ---------------------------------------------------------------------------
__global__ __launch_bounds__(256)
void f32_to_bf16(const float* __restrict__ in, u16* __restrict__ o, long n8)
{
  long i = (long)blockIdx.x*256 + threadIdx.x;
  if (i >= n8) return; i *= 8;
  f32x4 a = *(const f32x4*)&in[i], b = *(const f32x4*)&in[i+4];
  u16 w[8] __attribute__((aligned(16)));
  w[0]=f2bf(a.x);w[1]=f2bf(a.y);w[2]=f2bf(a.z);w[3]=f2bf(a.w);
  w[4]=f2bf(b.x);w[5]=f2bf(b.y);w[6]=f2bf(b.z);w[7]=f2bf(b.w);
  *(bf16x8*)&o[i] = *(bf16x8*)w;
}

__global__ __launch_bounds__(256)
void egather(const int* __restrict__ mods, const float* __restrict__ emb, u16* __restrict__ E)
{
  int i = blockIdx.x*256 + threadIdx.x;
  int row = i >> 3, j0 = (i & 7)*8;
  int m = mods[row]; if (m < 1) m = 1;
  const float* s = &emb[(long)m*64 + j0];
  f32x4 a = *(const f32x4*)s, b = *(const f32x4*)(s+4);
  u16 w[8] __attribute__((aligned(16)));
  w[0]=f2bf(a.x);w[1]=f2bf(a.y);w[2]=f2bf(a.z);w[3]=f2bf(a.w);
  w[4]=f2bf(b.x);w[5]=f2bf(b.y);w[6]=f2bf(b.z);w[7]=f2bf(b.w);
  *(bf16x8*)&E[(long)row*64 + j0] = *(bf16x8*)w;
}

__global__ __launch_bounds__(256)
void film_apply(const float* __restrict__ x, const u16* __restrict__ G,
                const u16* __restrict__ B, u16* __restrict__ y)
{
  long i = ((long)blockIdx.x*256 + threadIdx.x)*8;
  f32x4 x0 = *(const f32x4*)&x[i], x1 = *(const f32x4*)&x[i+4];
  bf16x8 g = *(const bf16x8*)&G[i], b = *(const bf16x8*)&B[i];
  float xv[8] = {x0.x,x0.y,x0.z,x0.w,x1.x,x1.y,x1.z,x1.w};
  u16 w[8] __attribute__((aligned(16)));
  #pragma unroll
  for (int e = 0; e < 8; e++)
    w[e] = f2bf((1.0f + bf2f((u16)g[e]))*xv[e] + bf2f((u16)b[e]));
  *(bf16x8*)&y[i] = *(bf16x8*)w;
}

__global__ __launch_bounds__(256)
void pack_bias(float* __restrict__ dst,
               const float* q_a, const float* k_a, const float* v_a,
               const float* q_e, const float* k_e, const float* v_e,
               const float* o_a, const float* o_e,
               const float* fg, const float* fb)
{
  int i = blockIdx.x*256 + threadIdx.x;
  if (i < 12288) {
    int br = i/6144, r = i - br*6144, sel = r >> 11, o = r & 2047;
    const float* s = br ? (sel==0?q_e:sel==1?k_e:v_e)
                        : (sel==0?q_a:sel==1?k_a:v_a);
    dst[i] = s[o];
  } else if (i < 16384) {
    int r = i - 12288; dst[i] = (r>>11) ? o_e[r&2047] : o_a[r&2047];
  } else {
    int r = i - 16384; dst[i] = (r>>11) ? fb[r&2047] : fg[r&2047];
  }
}

// ---------------------------------------------------------------------------
// LayerNorms
// ---------------------------------------------------------------------------
__global__ __launch_bounds__(256)
void ln_gate(const float* __restrict__ x, const u16* __restrict__ z0,
             const u16* __restrict__ z1, const float* __restrict__ ga,
             const float* __restrict__ g, const float* __restrict__ b,
             u16* __restrict__ h)
{
  __shared__ float red[8];
  long base = (long)blockIdx.x*DIM;
  int t8 = threadIdx.x*8, lane = threadIdx.x & 63, wid = threadIdx.x >> 6;
  float a0 = ga[0], a1 = ga[1];
  float mm = fmaxf(a0,a1), e0 = __expf(a0-mm), e1 = __expf(a1-mm);
  float w0 = e0/(e0+e1), w1 = e1/(e0+e1);
  f32x4 x0 = *(const f32x4*)&x[base+t8], x1 = *(const f32x4*)&x[base+t8+4];
  bf16x8 zi = *(const bf16x8*)&z0[base+t8], ze = *(const bf16x8*)&z1[base+t8];
  float xv[8] = {x0.x,x0.y,x0.z,x0.w,x1.x,x1.y,x1.z,x1.w};
  float v[8]; float s = 0.0f;
  #pragma unroll
  for (int j = 0; j < 8; j++) {
    v[j] = xv[j] + w0*bf2f((u16)zi[j]) + w1*bf2f((u16)ze[j]);
    s += v[j];
  }
  for (int o = 32; o; o >>= 1) s += __shfl_xor(s, o);
  if (lane == 0) red[wid] = s;
  __syncthreads();
  float mean = (red[0]+red[1]+red[2]+red[3])*(1.0f/DIM);
  float q = 0.0f;
  #pragma unroll
  for (int j = 0; j < 8; j++) { float d = v[j]-mean; q += d*d; }
  for (int o = 32; o; o >>= 1) q += __shfl_xor(q, o);
  if (lane == 0) red[4+wid] = q;
  __syncthreads();
  float inv = rsqrtf((red[4]+red[5]+red[6]+red[7])*(1.0f/DIM) + 1e-5f);
  f32x4 g0 = *(const f32x4*)&g[t8], g1 = *(const f32x4*)&g[t8+4];
  f32x4 b0 = *(const f32x4*)&b[t8], b1 = *(const f32x4*)&b[t8+4];
  float gv[8] = {g0.x,g0.y,g0.z,g0.w,g1.x,g1.y,g1.z,g1.w};
  float bv[8] = {b0.x,b0.y,b0.z,b0.w,b1.x,b1.y,b1.z,b1.w};
  u16 w[8] __attribute__((aligned(16)));
  #pragma unroll
  for (int j = 0; j < 8; j++) w[j] = f2bf((v[j]-mean)*inv*gv[j] + bv[j]);
  *(bf16x8*)&h[base+t8] = *(bf16x8*)w;
}

__global__ __launch_bounds__(256)
void ln_res(const u16* __restrict__ hin, const u16* __restrict__ y,
            const float* __restrict__ g, const float* __restrict__ b,
            float* __restrict__ out)
{
  __shared__ float red[8];
  long base = (long)blockIdx.x*DIM;
  int t8 = threadIdx.x*8, lane = threadIdx.x & 63, wid = threadIdx.x >> 6;
  bf16x8 hv = *(const bf16x8*)&hin[base+t8], yv = *(const bf16x8*)&y[base+t8];
  float v[8]; float s = 0.0f;
  #pragma unroll
  for (int j = 0; j < 8; j++) { v[j] = bf2f((u16)hv[j]) + bf2f((u16)yv[j]); s += v[j]; }
  for (int o = 32; o; o >>= 1) s += __shfl_xor(s, o);
  if (lane == 0) red[wid] = s;
  __syncthreads();
  float mean = (red[0]+red[1]+red[2]+red[3])*(1.0f/DIM);
  float q = 0.0f;
  #pragma unroll
  for (int j = 0; j < 8; j++) { float d = v[j]-mean; q += d*d; }
  for (int o = 32; o; o >>= 1) q += __shfl_xor(q, o);
  if (lane == 0) red[4+wid] = q;
  __syncthreads();
  float inv = rsqrtf((red[4]+red[5]+red[6]+red[7])*(1.0f/DIM) + 1e-5f);
  f32x4 g0 = *(const f32x4*)&g[t8], g1 = *(const f32x4*)&g[t8+4];
  f32x4 b0 = *(const f32x4*)&b[t8], b1 = *(const f32x4*)&b[t8+4];
  float gv[8] = {g0.x,g0.y,g0.z,g0.w,g1.x,g1.y,g1.z,g1.w};
  float bv[8] = {b0.x,b0.y,b0.z,b0.w,b1.x,b1.y,b1.z,b1.w};
  f32x4 o0, o1;
  #pragma unroll
  for (int j = 0; j < 4; j++) o0[j] = (v[j]-mean)*inv*gv[j] + bv[j];
  #pragma unroll
  for (int j = 0; j < 4; j++) o1[j] = (v[4+j]-mean)*inv*gv[4+j] + bv[4+j];
  *(f32x4*)&out[base+t8] = o0;
  *(f32x4*)&out[base+t8+4] = o1;
}

// ---------------------------------------------------------------------------
static void G4(hipStream_t st, const u16* A,int lda,long sAo,long sAi,
               const u16* B,int ldb,long sBo,long sBi,
               void* C,int ldc,long sCo,long sCi,int outbf,
               const float* bias,long sbias,int M,int N,int K,int batch,int hdiv,int relu)
{
  gemm4<<<dim3(N/128,M/128,batch),dim3(256),0,st>>>(
      A,lda,sAo,sAi,B,ldb,sBo,sBi,C,ldc,sCo,sCi,outbf,bias,sbias,K,hdiv,relu);
}
static void G4W(hipStream_t st, const u16* A,int lda,long sAo,long sAi,
                const u16* B,int ldb,long sBo,long sBi,
                u16* C,int ldc,long sCo,
                const float* bias,long sbias,int M,int N,int K,int batch,int hdiv,int relu)
{
  gemm4w<<<dim3(N/256,M/128,batch),dim3(256),0,st>>>(
      A,lda,sAo,sAi,B,ldb,sBo,sBi,C,ldc,sCo,bias,sbias,K,hdiv,relu);
}

extern "C" void kernel_launch(void* const* d_in, const int* in_sizes, int n_in,
                              void* d_out, int out_size, void* d_ws, size_t ws_size,
                              hipStream_t stream)
{
  const float* x          = (const float*)d_in[0];
  const float* mask_intra = (const float*)d_in[1];
  const float* mask_inter = (const float*)d_in[2];
  const int*   mods       = (const int*)  d_in[3];
  const float* film_emb   = (const float*)d_in[4];
  const float* film_gw    = (const float*)d_in[5];
  const float* film_gb    = (const float*)d_in[6];
  const float* film_bw    = (const float*)d_in[7];
  const float* film_bb    = (const float*)d_in[8];
  const float* gate_alpha = (const float*)d_in[9];
  const float* ln1_g = (const float*)d_in[10];
  const float* ln1_b = (const float*)d_in[11];
  const float* ln2_g = (const float*)d_in[12];
  const float* ln2_b = (const float*)d_in[13];
  const float* ffn_w1 = (const float*)d_in[14];
  const float* ffn_b1 = (const float*)d_in[15];
  const float* ffn_w2 = (const float*)d_in[16];
  const float* ffn_b2 = (const float*)d_in[17];
  const float* wq_a = (const float*)d_in[18]; const float* bq_a = (const float*)d_in[19];
  const float* wk_a = (const float*)d_in[20]; const float* bk_a = (const float*)d_in[21];
  const float* wv_a = (const float*)d_in[22]; const float* bv_a = (const float*)d_in[23];
  const float* wo_a = (const float*)d_in[24]; const float* bo_a = (const float*)d_in[25];
  const float* wq_e = (const float*)d_in[26]; const float* bq_e = (const float*)d_in[27];
  const float* wk_e = (const float*)d_in[28]; const float* bk_e = (const float*)d_in[29];
  const float* wv_e = (const float*)d_in[30]; const float* bv_e = (const float*)d_in[31];
  const float* wo_e = (const float*)d_in[32]; const float* bo_e = (const float*)d_in[33];

  // ---- lifetime-overlapped arena (audited R13) ----
  char* ws = (char*)d_ws;
  u16*   ybf  = (u16*)(ws);                      // 0..8Mi  y_intra (dead after QKV)
  u16*   xbf  = (u16*)(ws + (8L<<20));           // 8..16Mi x bf16 (dead after QKV)
  u16*   AO   = (u16*)(ws);                      // 0..16Mi attn out (PV -> out-proj)
  u16*   QKV  = (u16*)(ws + (16L<<20));          // 16..64Mi (dead after vtrans/qkprobs)
  u16*   Gf   = QKV;
  u16*   Bfm  = QKV + DSZ;
  u16*   zbuf = (u16*)(ws + (16L<<20));          // 16..32 (out-proj out; QKV dead)
  u16*   hbf  = (u16*)(ws + (32L<<20));          // 32..40
  u16*   Wst  = (u16*)(ws + (64L<<20));          // 64..96 weight staging
  u16*   Pall = (u16*)(ws + (96L<<20));          // 96..160 probs both branches
  u16*   mid  = (u16*)(ws + (96L<<20));          // 96..128 ffn mid (P dead by FFN)
  float* Pf2  = (float*)(ws + (128L<<20));       // 128..160 ffn2 partials (P dead)
  u16*   f2o  = (u16*)(ws + (16L<<20));          // 16..24 ffn2 out (zbuf dead after ln_gate)
  u16*   Vt   = (u16*)(ws + (160L<<20));         // 160..176 V^T both branches
  u16*   Ebuf = (u16*)(ws + (160L<<20));         //   (pre-Vt)
  u16*   Wfm  = (u16*)(ws + (161L<<20));         //   (pre-Vt)
  float* bpk  = (float*)(ws + (176L<<20));       // packed biases (80 KiB)

  // ---- conversions + packing ----
  f32_to_bf16<<<2048,256,0,stream>>>(x, xbf, DSZ/8);
  egather<<<64,256,0,stream>>>(mods, film_emb, Ebuf);
  {
    P6 pf; pf.p[0]=film_gw; pf.p[1]=film_bw;
    pf.p[2]=film_gw; pf.p[3]=film_gw; pf.p[4]=film_gw; pf.p[5]=film_gw;
    wtrans6<<<dim3(32,1,2),256,0,stream>>>(pf, DIM, Wfm, (long)DIM*64, 64);
  }
  pack_bias<<<80,256,0,stream>>>(bpk, bq_a,bk_a,bv_a, bq_e,bk_e,bv_e, bo_a,bo_e, film_gb,film_bb);

  // ---- FiLM: [G|B] = E @ [gw|bw] + bias (gemm4, z=2, K=64) ----
  G4(stream, Ebuf,64,0,0, Wfm,64,(long)DIM*64,0, Gf,DIM,DSZ,0,1,
     bpk+16384,2048, BTOK,DIM,64, 2,1, 0);
  film_apply<<<2048,256,0,stream>>>(x, Gf, Bfm, ybf);

  // ---- QKV both branches (gemm4w, z=2) ----
  {
    P6 pq; pq.p[0]=wq_a; pq.p[1]=wk_a; pq.p[2]=wv_a;
    pq.p[3]=wq_e; pq.p[4]=wk_e; pq.p[5]=wv_e;
    wtrans6<<<dim3(32,32,6),256,0,stream>>>(pq, DIM, Wst, (long)DIM*DIM, DIM);
  }
  G4W(stream, ybf,DIM,DSZ,0, Wst,DIM,(long)QKVN*DIM,0, QKV,QKVN,QKVSZ,
      bpk,QKVN, BTOK,QKVN,DIM, 2,1, 0);

  // ---- attention: vtrans(both) ; qkprobs(both, BM=32) ; PV(both, gemm4) ----
  vtrans_both<<<dim3(8,2,128),256,0,stream>>>(QKV, Vt);
  qkprobs_both<<<dim3(128,16),dim3(256),0,stream>>>(QKV, mask_intra, mask_inter, Pall);
  G4(stream, Pall,SEQ,(long)16*SEQ*SEQ,(long)SEQ*SEQ,
     Vt,SEQ,(long)16*HDIM*SEQ,(long)HDIM*SEQ,
     AO,DIM,(long)SEQ*DIM,HDIM,1, nullptr,0,
     SEQ,HDIM,SEQ, 128,16, 0);

  // ---- out-proj (gemm4, z=2) -> z bf16 ----
  {
    P6 po; po.p[0]=wo_a; po.p[1]=wo_e;
    po.p[2]=wo_a; po.p[3]=wo_a; po.p[4]=wo_a; po.p[5]=wo_a;
    wtrans6<<<dim3(32,32,2),256,0,stream>>>(po, DIM, Wst, (long)DIM*DIM, DIM);
  }
  G4(stream, AO,DIM,DSZ,0, Wst,DIM,(long)DIM*DIM,0, zbuf,DIM,DSZ,0,1,
     bpk+12288,DIM, BTOK,DIM,DIM, 2,1, 0);

  // ---- gate + LN1 ----
  ln_gate<<<2048,256,0,stream>>>(x, zbuf, zbuf+DSZ, gate_alpha, ln1_g, ln1_b, hbf);

  // ---- FFN ----
  wtrans<<<dim3(128,32),256,0,stream>>>(ffn_w1, FFDIM, Wst, DIM);
  G4W(stream, hbf,DIM,0,0, Wst,DIM,0,0, mid,FFDIM,0,
      ffn_b1,0, BTOK,FFDIM,DIM, 1,1, 1);                                   // relu
  wtrans<<<dim3(32,128),256,0,stream>>>(ffn_w2, DIM, Wst, FFDIM);
  // FFN2 split-K x2 -> grid (16,16,2)=512 blocks
  G4(stream, mid,FFDIM,4096,0, Wst,FFDIM,4096,0, Pf2,DIM,DSZ,0,0,
     nullptr,0, BTOK,DIM,4096, 2,1, 0);
  redk<<<2048,256,0,stream>>>(Pf2, 2, ffn_b2, f2o);

  // ---- LN2 -> out ----
  ln_res<<<2048,256,0,stream>>>(hbf, f2o, ln2_g, ln2_b, (float*)d_out);
}

// Round 21
// 584.179 us; speedup vs baseline: 1.0302x; 1.0002x over previous
//
#include <hip/hip_runtime.h>
#include <hip/hip_bf16.h>

typedef float f32x4 __attribute__((ext_vector_type(4)));
typedef short bf16x8 __attribute__((ext_vector_type(8)));
typedef unsigned short u16;

#define SEQ    512
#define DIM    2048
#define NHEAD  16
#define HDIM   128
#define BATCH  4
#define BTOK   2048
#define FFDIM  8192
#define DSZ    ((long)BTOK*DIM)       // 4,194,304 elements (2^22)
#define QKVN   (3*DIM)                // 6144
#define QKVSZ  ((long)BTOK*QKVN)
#define ISS    0.08838834764831845f   // 1/sqrt(128)

__device__ __forceinline__ u16 f2bf(float f){
  union{float fv;unsigned u;}c;c.fv=f;
  unsigned r=c.u+0x7FFFu+((c.u>>16)&1u); return (u16)(r>>16);
}
__device__ __forceinline__ float bf2f(u16 v){
  union{unsigned u;float f;}c;c.u=((unsigned)v)<<16;return c.f;
}
__device__ __forceinline__ float pow103(float t){
  return __builtin_amdgcn_exp2f(__builtin_amdgcn_logf(t)*(10.0f/3.0f));
}

// async global->LDS, 16B per lane, LDS dest = wave-uniform base + lane*16
#define GLD16(g,l) __builtin_amdgcn_global_load_lds( \
    (const __attribute__((address_space(1))) unsigned int*)(g), \
    (__attribute__((address_space(3))) unsigned int*)(l), 16, 0, 0)

#define MF(a,b,c) __builtin_amdgcn_mfma_f32_16x16x32_bf16(a,b,c,0,0,0)
#define VMW(n) do{ asm volatile("s_waitcnt vmcnt(" #n ")" ::: "memory"); \
                   __builtin_amdgcn_sched_barrier(0); }while(0)
#define LGKM0() do{ asm volatile("s_waitcnt lgkmcnt(0)" ::: "memory"); \
                    __builtin_amdgcn_sched_barrier(0); }while(0)
#define BARR() do{ asm volatile("" ::: "memory"); __builtin_amdgcn_s_barrier(); \
                   asm volatile("" ::: "memory"); }while(0)

// ---------------------------------------------------------------------------
// gemm4w: 128x256 block, 4 waves (each 128x64, 8x4 acc), BK=32, 3-deep
// pipeline, 72 KiB LDS -> 2 blocks/CU. Verified R12/R18 (35.6% MfmaUtil).
// Used for FFN1 (grid 512 = exactly 2/CU capacity -> no tail).
// ---------------------------------------------------------------------------
__global__ __launch_bounds__(256, 2)
void gemm4w(const u16* __restrict__ A, int lda, long sAo, long sAi,
            const u16* __restrict__ B, int ldb, long sBo, long sBi,
            u16* __restrict__ C, int ldc, long sCo,
            const float* __restrict__ bias, long sbias,
            int K, int hdiv, int relu)
{
  __shared__ __align__(16) u16 sm[36864];     // 72 KiB = 3 x (8K A + 16K B)
  char* smb = (char*)sm;

  int gx = gridDim.x, gy = gridDim.y;
  int nwg = gx*gy*gridDim.z;
  int flat = (blockIdx.z*gy + blockIdx.y)*gx + blockIdx.x;
  int cpx = nwg >> 3; flat = (flat & 7)*cpx + (flat >> 3);
  int by = flat % gy; int tq = flat / gy; int bx = tq % gx; int bz = tq / gx;

  int zo = bz / hdiv, zi = bz - zo*hdiv;
  const u16* Ab = A + (long)zo*sAo + (long)zi*sAi;
  const u16* Bb = B + (long)zo*sBo + (long)zi*sBi;
  int m0 = by*128, n0 = bx*256;

  int tid = threadIdx.x, lane = tid & 63, w = tid >> 6;
  int lr = lane & 15, lg = lane >> 4;
  int rl = lane >> 2, cbyte = (lane & 3)*16;

  int sRA[2], sCA[2];
  #pragma unroll
  for (int q = 0; q < 2; q++) {
    int r = (2*w+q)*16 + rl;
    sRA[q] = r ^ ((r>>2)&1);
    sCA[q] = (cbyte ^ ((((r>>2)^r)&1)<<4) ^ (((r>>1)&1)<<5)) >> 1;
  }
  int sRB[4], sCB[4];
  #pragma unroll
  for (int q = 0; q < 4; q++) {
    int r = (4*w+q)*16 + rl;
    sRB[q] = r ^ ((r>>2)&1);
    sCB[q] = (cbyte ^ ((((r>>2)^r)&1)<<4) ^ (((r>>1)&1)<<5)) >> 1;
  }

  int aoff = (lr*64 + lg*16) ^ ((lane&7)<<4);
  int boff = w*4096 + ((lr*64 + lg*16) ^ ((lane&7)<<4));

  f32x4 acc[8][4] = {};
  int NT = K >> 5;

  auto STG = [&](int buf, int kt) {
    int kcol = kt*32;
    char* base = smb + buf*24576;
    #pragma unroll
    for (int q = 0; q < 2; q++)
      GLD16(Ab + (long)(m0 + sRA[q])*lda + kcol + sCA[q], base + (2*w+q)*1024);
    #pragma unroll
    for (int q = 0; q < 4; q++)
      GLD16(Bb + (long)(n0 + sRB[q])*ldb + kcol + sCB[q], base + 8192 + (4*w+q)*1024);
  };

  STG(0,0);
  if (NT > 1) STG(1,1);

  int buf = 0;
  for (int t = 0; t < NT; t++) {
    char* Ax = smb + buf*24576;
    char* Bx = Ax + 8192;

    if (t+2 < NT) {
      int nb = buf + 2; if (nb >= 3) nb -= 3;
      STG(nb, t+2);
      VMW(12);
    } else if (t+1 < NT) { VMW(6); }
    else                 { VMW(0); }
    BARR();

    bf16x8 af[8], bv[4];
    #pragma unroll
    for (int i = 0; i < 8; i++) af[i] = *(const bf16x8*)(Ax + aoff + i*1024);
    #pragma unroll
    for (int j = 0; j < 4; j++) bv[j] = *(const bf16x8*)(Bx + boff + j*1024);
    LGKM0();
    __builtin_amdgcn_s_setprio(1);
    #pragma unroll
    for (int i = 0; i < 8; i++) {
      acc[i][0] = MF(af[i], bv[0], acc[i][0]);
      acc[i][1] = MF(af[i], bv[1], acc[i][1]);
      acc[i][2] = MF(af[i], bv[2], acc[i][2]);
      acc[i][3] = MF(af[i], bv[3], acc[i][3]);
    }
    __builtin_amdgcn_s_setprio(0);
    BARR();
    buf++; if (buf == 3) buf = 0;
  }

  u16* Cb = C + (long)bz*sCo;
  #pragma unroll
  for (int j = 0; j < 4; j++) {
    int col = n0 + w*64 + j*16 + lr;
    float bv2 = bias ? bias[zo*sbias + col] : 0.0f;
    #pragma unroll
    for (int i = 0; i < 8; i++) {
      #pragma unroll
      for (int e = 0; e < 4; e++) {
        int row = m0 + i*16 + lg*4 + e;
        float v = acc[i][j][e] + bv2;
        if (relu) v = fmaxf(v, 0.0f);
        Cb[(long)row*ldc + col] = f2bf(v);
      }
    }
  }
}

// ---------------------------------------------------------------------------
// gemm4w2: R21 — same 128x256/4-wave tile but 2-buffer pipeline, 48 KiB LDS
// -> 3 blocks/CU (=768 co-resident, exactly QKV's grid; kills the 768-vs-512
// residency tail that capped QKV Occupancy at 17%). Stage t+1 during t,
// VMW(6) certifies tile t (6 in flight for t+1). Used for QKV only.
// ---------------------------------------------------------------------------
__global__ __launch_bounds__(256, 2)
void gemm4w2(const u16* __restrict__ A, int lda, long sAo, long sAi,
             const u16* __restrict__ B, int ldb, long sBo, long sBi,
             u16* __restrict__ C, int ldc, long sCo,
             const float* __restrict__ bias, long sbias,
             int K, int hdiv, int relu)
{
  __shared__ __align__(16) u16 sm[24576];     // 48 KiB = 2 x (8K A + 16K B)
  char* smb = (char*)sm;

  int gx = gridDim.x, gy = gridDim.y;
  int nwg = gx*gy*gridDim.z;
  int flat = (blockIdx.z*gy + blockIdx.y)*gx + blockIdx.x;
  int cpx = nwg >> 3; flat = (flat & 7)*cpx + (flat >> 3);
  int by = flat % gy; int tq = flat / gy; int bx = tq % gx; int bz = tq / gx;

  int zo = bz / hdiv, zi = bz - zo*hdiv;
  const u16* Ab = A + (long)zo*sAo + (long)zi*sAi;
  const u16* Bb = B + (long)zo*sBo + (long)zi*sBi;
  int m0 = by*128, n0 = bx*256;

  int tid = threadIdx.x, lane = tid & 63, w = tid >> 6;
  int lr = lane & 15, lg = lane >> 4;
  int rl = lane >> 2, cbyte = (lane & 3)*16;

  int sRA[2], sCA[2];
  #pragma unroll
  for (int q = 0; q < 2; q++) {
    int r = (2*w+q)*16 + rl;
    sRA[q] = r ^ ((r>>2)&1);
    sCA[q] = (cbyte ^ ((((r>>2)^r)&1)<<4) ^ (((r>>1)&1)<<5)) >> 1;
  }
  int sRB[4], sCB[4];
  #pragma unroll
  for (int q = 0; q < 4; q++) {
    int r = (4*w+q)*16 + rl;
    sRB[q] = r ^ ((r>>2)&1);
    sCB[q] = (cbyte ^ ((((r>>2)^r)&1)<<4) ^ (((r>>1)&1)<<5)) >> 1;
  }

  int aoff = (lr*64 + lg*16) ^ ((lane&7)<<4);
  int boff = w*4096 + ((lr*64 + lg*16) ^ ((lane&7)<<4));

  f32x4 acc[8][4] = {};
  int NT = K >> 5;

  auto STG = [&](int buf, int kt) {
    int kcol = kt*32;
    char* base = smb + buf*24576;
    #pragma unroll
    for (int q = 0; q < 2; q++)
      GLD16(Ab + (long)(m0 + sRA[q])*lda + kcol + sCA[q], base + (2*w+q)*1024);
    #pragma unroll
    for (int q = 0; q < 4; q++)
      GLD16(Bb + (long)(n0 + sRB[q])*ldb + kcol + sCB[q], base + 8192 + (4*w+q)*1024);
  };

  STG(0,0);

  int buf = 0;
  for (int t = 0; t < NT; t++) {
    char* Ax = smb + buf*24576;
    char* Bx = Ax + 8192;

    if (t+1 < NT) { STG(buf^1, t+1); VMW(6); }  // 12 in flight -> drain t's 6
    else          { VMW(0); }
    BARR();

    bf16x8 af[8], bv[4];
    #pragma unroll
    for (int i = 0; i < 8; i++) af[i] = *(const bf16x8*)(Ax + aoff + i*1024);
    #pragma unroll
    for (int j = 0; j < 4; j++) bv[j] = *(const bf16x8*)(Bx + boff + j*1024);
    LGKM0();
    __builtin_amdgcn_s_setprio(1);
    #pragma unroll
    for (int i = 0; i < 8; i++) {
      acc[i][0] = MF(af[i], bv[0], acc[i][0]);
      acc[i][1] = MF(af[i], bv[1], acc[i][1]);
      acc[i][2] = MF(af[i], bv[2], acc[i][2]);
      acc[i][3] = MF(af[i], bv[3], acc[i][3]);
    }
    __builtin_amdgcn_s_setprio(0);
    BARR();
    buf ^= 1;
  }

  u16* Cb = C + (long)bz*sCo;
  #pragma unroll
  for (int j = 0; j < 4; j++) {
    int col = n0 + w*64 + j*16 + lr;
    float bv2 = bias ? bias[zo*sbias + col] : 0.0f;
    #pragma unroll
    for (int i = 0; i < 8; i++) {
      #pragma unroll
      for (int e = 0; e < 4; e++) {
        int row = m0 + i*16 + lg*4 + e;
        float v = acc[i][j][e] + bv2;
        if (relu) v = fmaxf(v, 0.0f);
        Cb[(long)row*ldc + col] = f2bf(v);
      }
    }
  }
}

// ---------------------------------------------------------------------------
// gemm4: 128x128 tile, BK=32, 4 waves, 3-deep pipeline, 48 KiB LDS
// (3 blocks/CU). C offset = zo*sCo + zi*sCi (supports per-head PV output).
// ---------------------------------------------------------------------------
__global__ __launch_bounds__(256, 3)
void gemm4(const u16* __restrict__ A, int lda, long sAo, long sAi,
           const u16* __restrict__ B, int ldb, long sBo, long sBi,
           void* __restrict__ C, int ldc, long sCo, long sCi, int outbf,
           const float* __restrict__ bias, long sbias,
           int K, int hdiv, int relu)
{
  __shared__ __align__(16) u16 sm[24576];     // 48 KiB
  char* smb = (char*)sm;

  int gx = gridDim.x, gy = gridDim.y;
  int nwg = gx*gy*gridDim.z;
  int flat = (blockIdx.z*gy + blockIdx.y)*gx + blockIdx.x;
  int cpx = nwg >> 3; flat = (flat & 7)*cpx + (flat >> 3);
  int by = flat % gy; int tq = flat / gy; int bx = tq % gx; int bz = tq / gx;

  int zo = bz / hdiv, zi = bz - zo*hdiv;
  const u16* Ab = A + (long)zo*sAo + (long)zi*sAi;
  const u16* Bb = B + (long)zo*sBo + (long)zi*sBi;
  int m0 = by*128, n0 = bx*128;

  int tid = threadIdx.x, lane = tid & 63, w = tid >> 6;
  int wrow = (w>>1)*64, wn = (w&1)*64;
  int lr = lane & 15, lg = lane >> 4;

  int stR[2], stC[2], ldsch[2];
  #pragma unroll
  for (int q = 0; q < 2; q++) {
    int chunk = q*4 + w;
    int r = chunk*16 + (lane>>2);
    int c = (lane&3)*16;
    int Rz = r ^ ((r>>2)&1);
    int Cz = c ^ ((((r>>2)^r)&1)<<4) ^ (((r>>1)&1)<<5);
    stR[q] = Rz; stC[q] = Cz>>1;
    ldsch[q] = chunk*1024;
  }

  int aoff = ((wrow + lr)*64 + lg*16) ^ ((lane&7)<<4);
  int boff = ((wn  + lr)*64 + lg*16) ^ ((lane&7)<<4);

  f32x4 acc[4][4] = {};
  int NT = K >> 5;

  auto STG = [&](int buf, int op, int kt) {
    const u16* gp = op ? Bb : Ab;
    int ld   = op ? ldb : lda;
    int base = op ? n0 : m0;
    int kcol = kt*32;
    #pragma unroll
    for (int q = 0; q < 2; q++) {
      const u16* src = gp + (long)(base + stR[q])*ld + kcol + stC[q];
      char* dst = smb + buf*16384 + op*8192 + ldsch[q];
      GLD16(src, dst);
    }
  };

  STG(0,0,0); STG(0,1,0);
  if (NT > 1) { STG(1,0,1); STG(1,1,1); }

  int buf = 0;
  for (int t = 0; t < NT; t++) {
    char* Ax = smb + buf*16384;
    char* Bx = smb + buf*16384 + 8192;

    if (t+2 < NT) {
      int nb = buf + 2; if (nb >= 3) nb -= 3;
      STG(nb,0,t+2); STG(nb,1,t+2);
      VMW(8);
    } else if (t+1 < NT) { VMW(4); }
    else                 { VMW(0); }
    BARR();

    bf16x8 af[4], bv[4];
    #pragma unroll
    for (int i = 0; i < 4; i++) af[i] = *(const bf16x8*)(Ax + aoff + i*1024);
    #pragma unroll
    for (int j = 0; j < 4; j++) bv[j] = *(const bf16x8*)(Bx + boff + j*1024);
    LGKM0();
    __builtin_amdgcn_s_setprio(1);
    #pragma unroll
    for (int i = 0; i < 4; i++) {
      acc[i][0] = MF(af[i], bv[0], acc[i][0]);
      acc[i][1] = MF(af[i], bv[1], acc[i][1]);
      acc[i][2] = MF(af[i], bv[2], acc[i][2]);
      acc[i][3] = MF(af[i], bv[3], acc[i][3]);
    }
    __builtin_amdgcn_s_setprio(0);
    BARR();
    buf++; if (buf == 3) buf = 0;
  }

  long coff = (long)zo*sCo + (long)zi*sCi;
  if (outbf) {
    u16* Cb = (u16*)C + coff;
    #pragma unroll
    for (int j = 0; j < 4; j++) {
      int col = n0 + wn + j*16 + lr;
      float bv2 = bias ? bias[zo*sbias + col] : 0.0f;
      #pragma unroll
      for (int i = 0; i < 4; i++) {
        #pragma unroll
        for (int e = 0; e < 4; e++) {
          int row = m0 + wrow + i*16 + lg*4 + e;
          float v = acc[i][j][e] + bv2;
          if (relu) v = fmaxf(v, 0.0f);
          Cb[(long)row*ldc + col] = f2bf(v);
        }
      }
    }
  } else {
    float* Cb = (float*)C + coff;
    #pragma unroll
    for (int j = 0; j < 4; j++) {
      int col = n0 + wn + j*16 + lr;
      #pragma unroll
      for (int i = 0; i < 4; i++) {
        #pragma unroll
        for (int e = 0; e < 4; e++) {
          int row = m0 + wrow + i*16 + lg*4 + e;
          Cb[(long)row*ldc + col] = acc[i][j][e];
        }
      }
    }
  }
}

// ---------------------------------------------------------------------------
// qkprobs_both: grid (128, 16): x = br*64+head, y = q-tile (BM=32).
// 40KB LDS (A 8K + K 32K single-buffered), launch_bounds(256,2): compiler
// settles ~116 VGPR, zero spill (R18: WRITE = 64MB exactly). acc[2][8] =
// 64 VGPR score tile fits in registers. Solver: 5 bisect + 3 monotone Newton.
// ---------------------------------------------------------------------------
__global__ __launch_bounds__(256, 2)
void qkprobs_both(const u16* __restrict__ QKVp,
                  const float* __restrict__ maskI, const float* __restrict__ maskE,
                  u16* __restrict__ Pall)
{
  __shared__ __align__(16) u16 sm[20480];      // 40 KiB: A 8K + K 32K
  char* smb = (char*)sm;

  int z2 = blockIdx.x;
  int m0 = blockIdx.y*32;
  int br = z2 >> 6, z = z2 & 63;
  int b  = z >> 4, h = z & 15;
  const float* maskp = br ? maskE : maskI;
  const u16* Qb = QKVp + (long)br*QKVSZ + (long)b*SEQ*QKVN + h*HDIM;
  const u16* Kb = Qb + DIM;
  u16* P = Pall + (long)br*64*SEQ*SEQ;

  int tid = threadIdx.x, lane = tid & 63, w = tid >> 6;
  int lr = lane & 15, lg = lane >> 4;
  int wn = w*128;

  int rl = lane >> 2;
  int cb = (lane & 3)*16;

  int aoff = (lr*64 + lg*16) ^ ((lane&7)<<4);
  int boff = ((wn + lr)*64 + lg*16) ^ ((lane&7)<<4);

  auto stgA = [&](int kt) {
    int r = (w&1)*16 + rl;
    int Rz = r ^ ((r>>2)&1);
    int Cz = cb ^ ((((r>>2)^r)&1)<<4) ^ (((r>>1)&1)<<5);
    GLD16(Qb + (long)(m0+Rz)*QKVN + kt*32 + (Cz>>1), smb + kt*2048 + (w&1)*1024);
  };
  auto stgB = [&](int kt) {
    #pragma unroll
    for (int q = 0; q < 8; q++) {
      int chunk = q*4 + w;
      int r = chunk*16 + rl;
      int Rz = r ^ ((r>>2)&1);
      int Cz = cb ^ ((((r>>2)^r)&1)<<4) ^ (((r>>1)&1)<<5);
      GLD16(Kb + (long)Rz*QKVN + kt*32 + (Cz>>1),
            smb + 8192 + chunk*1024);
    }
  };

  f32x4 acc[2][8] = {};                        // 64 VGPRs

  stgA(0); stgA(1); stgA(2); stgA(3);
  stgB(0);

  #pragma unroll
  for (int kt = 0; kt < 4; kt++) {
    VMW(0);
    BARR();
    char* Bx = smb + 8192;
    bf16x8 af[2], bv[8];
    #pragma unroll
    for (int i = 0; i < 2; i++) af[i] = *(const bf16x8*)(smb + kt*2048 + aoff + i*1024);
    #pragma unroll
    for (int j = 0; j < 8; j++) bv[j] = *(const bf16x8*)(Bx + boff + j*1024);
    LGKM0();
    BARR();
    if (kt < 3) stgB(kt+1);
    __builtin_amdgcn_s_setprio(1);
    #pragma unroll
    for (int i = 0; i < 2; i++)
      #pragma unroll
      for (int j = 0; j < 8; j++)
        acc[i][j] = MF(af[i], bv[j], acc[i][j]);
    __builtin_amdgcn_s_setprio(0);
  }

  float* redA = (float*)smb;
  float* redB = (float*)(smb + 512);

  float rmax[8];
  #pragma unroll
  for (int s = 0; s < 8; s++) rmax[s] = -3.4e38f;
  #pragma unroll
  for (int i = 0; i < 2; i++) {
    #pragma unroll
    for (int e = 0; e < 4; e++) {
      int row = i*16 + lg*4 + e;
      const float* mp = maskp + (long)(m0+row)*SEQ + wn + lr;
      #pragma unroll
      for (int j = 0; j < 8; j++) {
        float v = acc[i][j][e]*ISS + mp[j*16];
        acc[i][j][e] = v;
        rmax[i*4+e] = fmaxf(rmax[i*4+e], v);
      }
    }
  }
  #pragma unroll
  for (int s = 0; s < 8; s++)
    #pragma unroll
    for (int o = 1; o < 16; o <<= 1) rmax[s] = fmaxf(rmax[s], __shfl_xor(rmax[s], o));
  if (lr == 0) {
    #pragma unroll
    for (int i = 0; i < 2; i++)
      #pragma unroll
      for (int e = 0; e < 4; e++) redA[w*32 + i*16 + lg*4 + e] = rmax[i*4+e];
  }
  BARR();
  #pragma unroll
  for (int i = 0; i < 2; i++)
    #pragma unroll
    for (int e = 0; e < 4; e++) {
      int row = i*16 + lg*4 + e;
      rmax[i*4+e] = fmaxf(fmaxf(redA[row], redA[32+row]),
                          fmaxf(redA[64+row], redA[96+row]));
    }
  BARR();

  float inv[8];

  if (br) {
    #pragma unroll
    for (int i = 0; i < 2; i++)
      #pragma unroll
      for (int j = 0; j < 8; j++)
        #pragma unroll
        for (int e = 0; e < 4; e++)
          acc[i][j][e] = (acc[i][j][e] - rmax[i*4+e])*0.3f;

    float lo[8];
    #pragma unroll
    for (int s = 0; s < 8; s++) lo[s] = -1.0f;    // s(-1) >= 1
    float half = 0.5f;

    #pragma unroll 1
    for (int it = 0; it < 5; it++) {              // bisection, lo-only
      float ps[8];
      #pragma unroll
      for (int s = 0; s < 8; s++) ps[s] = 0.0f;
      #pragma unroll
      for (int i = 0; i < 2; i++)
        #pragma unroll
        for (int e = 0; e < 4; e++) {
          float mid = lo[i*4+e] + half;
          #pragma unroll
          for (int j = 0; j < 8; j++) {
            float t = acc[i][j][e] - mid;
            if (t > 0.0f) ps[i*4+e] += pow103(t);
          }
        }
      #pragma unroll
      for (int s = 0; s < 8; s++)
        #pragma unroll
        for (int o = 1; o < 16; o <<= 1) ps[s] += __shfl_xor(ps[s], o);
      if (lr == 0) {
        #pragma unroll
        for (int i = 0; i < 2; i++)
          #pragma unroll
          for (int e = 0; e < 4; e++) redA[w*32 + i*16 + lg*4 + e] = ps[i*4+e];
      }
      BARR();
      #pragma unroll
      for (int i = 0; i < 2; i++)
        #pragma unroll
        for (int e = 0; e < 4; e++) {
          int row = i*16 + lg*4 + e, s = i*4+e;
          float tot = redA[row] + redA[32+row] + redA[64+row] + redA[96+row];
          if (tot > 1.0f) lo[s] += half;          // keep s(lo) >= 1
        }
      BARR();
      half *= 0.5f;
    }

    #pragma unroll 1
    for (int it = 0; it < 3; it++) {              // pure Newton (monotone)
      float ps[8], pd[8];
      #pragma unroll
      for (int s = 0; s < 8; s++) { ps[s] = 0.0f; pd[s] = 0.0f; }
      #pragma unroll
      for (int i = 0; i < 2; i++)
        #pragma unroll
        for (int e = 0; e < 4; e++) {
          float tv = lo[i*4+e];
          #pragma unroll
          for (int j = 0; j < 8; j++) {
            float t = acc[i][j][e] - tv;
            if (t > 0.0f) {
              float w7 = __builtin_amdgcn_exp2f(__builtin_amdgcn_logf(t)*(7.0f/3.0f));
              pd[i*4+e] += w7; ps[i*4+e] += w7*t;
            }
          }
        }
      #pragma unroll
      for (int s = 0; s < 8; s++)
        #pragma unroll
        for (int o = 1; o < 16; o <<= 1) {
          ps[s] += __shfl_xor(ps[s], o);
          pd[s] += __shfl_xor(pd[s], o);
        }
      if (lr == 0) {
        #pragma unroll
        for (int i = 0; i < 2; i++)
          #pragma unroll
          for (int e = 0; e < 4; e++) {
            redA[w*32 + i*16 + lg*4 + e] = ps[i*4+e];
            redB[w*32 + i*16 + lg*4 + e] = pd[i*4+e];
          }
      }
      BARR();
      #pragma unroll
      for (int i = 0; i < 2; i++)
        #pragma unroll
        for (int e = 0; e < 4; e++) {
          int row = i*16 + lg*4 + e, s = i*4+e;
          float st = redA[row] + redA[32+row] + redA[64+row] + redA[96+row];
          float dt = redB[row] + redB[32+row] + redB[64+row] + redB[96+row];
          lo[s] += (st - 1.0f) / ((10.0f/3.0f)*dt + 1e-30f);
        }
      BARR();
    }

    float ps[8];
    #pragma unroll
    for (int s = 0; s < 8; s++) ps[s] = 0.0f;
    #pragma unroll
    for (int i = 0; i < 2; i++)
      #pragma unroll
      for (int e = 0; e < 4; e++) {
        float tv = lo[i*4+e];
        #pragma unroll
        for (int j = 0; j < 8; j++) {
          float t = acc[i][j][e] - tv;
          float p = (t > 0.0f) ? pow103(t) : 0.0f;
          acc[i][j][e] = p;
          ps[i*4+e] += p;
        }
      }
    #pragma unroll
    for (int s = 0; s < 8; s++)
      #pragma unroll
      for (int o = 1; o < 16; o <<= 1) ps[s] += __shfl_xor(ps[s], o);
    if (lr == 0) {
      #pragma unroll
      for (int i = 0; i < 2; i++)
        #pragma unroll
        for (int e = 0; e < 4; e++) redA[w*32 + i*16 + lg*4 + e] = ps[i*4+e];
    }
    BARR();
    #pragma unroll
    for (int i = 0; i < 2; i++)
      #pragma unroll
      for (int e = 0; e < 4; e++) {
        int row = i*16 + lg*4 + e;
        inv[i*4+e] = 1.0f/(redA[row] + redA[32+row] + redA[64+row] + redA[96+row] + 1e-12f);
      }
  } else {
    float ps[8];
    #pragma unroll
    for (int s = 0; s < 8; s++) ps[s] = 0.0f;
    #pragma unroll
    for (int i = 0; i < 2; i++)
      #pragma unroll
      for (int e = 0; e < 4; e++) {
        float mx = rmax[i*4+e];
        #pragma unroll
        for (int j = 0; j < 8; j++) {
          float p = __expf(acc[i][j][e] - mx);
          acc[i][j][e] = p;
          ps[i*4+e] += p;
        }
      }
    #pragma unroll
    for (int s = 0; s < 8; s++)
      #pragma unroll
      for (int o = 1; o < 16; o <<= 1) ps[s] += __shfl_xor(ps[s], o);
    if (lr == 0) {
      #pragma unroll
      for (int i = 0; i < 2; i++)
        #pragma unroll
        for (int e = 0; e < 4; e++) redA[w*32 + i*16 + lg*4 + e] = ps[i*4+e];
    }
    BARR();
    #pragma unroll
    for (int i = 0; i < 2; i++)
      #pragma unroll
      for (int e = 0; e < 4; e++) {
        int row = i*16 + lg*4 + e;
        inv[i*4+e] = 1.0f/(redA[row] + redA[32+row] + redA[64+row] + redA[96+row]);
      }
  }

  // ---- LDS repack: [32 rows][512 cols] u16 (32 KB) in dead K region ----
  BARR();
  char* rp = smb + 8192;
  #pragma unroll
  for (int i = 0; i < 2; i++)
    #pragma unroll
    for (int e = 0; e < 4; e++) {
      int r = i*16 + lg*4 + e;
      float sc = inv[i*4+e];
      #pragma unroll
      for (int j = 0; j < 8; j++) {
        int cbyt = (wn + j*16 + lr)*2;
        *(u16*)(rp + r*1024 + (cbyt ^ ((r&7)<<4))) = f2bf(acc[i][j][e]*sc);
      }
    }
  BARR();
  u16* Pb = P + ((long)z*SEQ + m0)*SEQ;
  #pragma unroll
  for (int chunk = 0; chunk < 8; chunk++) {
    int p = chunk*4096 + tid*16;
    int row = p >> 10, cb2 = p & 1023;
    bf16x8 v = *(const bf16x8*)(rp + row*1024 + (cb2 ^ ((row&7)<<4)));
    *(bf16x8*)((char*)Pb + p) = v;
  }
}

// ---------------------------------------------------------------------------
// split-K reduce
// ---------------------------------------------------------------------------
__global__ __launch_bounds__(256)
void redk(const float* __restrict__ Pp, int nk, const float* __restrict__ bias,
          u16* __restrict__ out)
{
  long i = ((long)blockIdx.x*256 + threadIdx.x)*8;
  long z = i >> 22;
  int  n = (int)(i & 2047);
  float v[8] = {};
  for (int k = 0; k < nk; k++) {
    const float* s = Pp + (z*nk + k)*DSZ + (i & (DSZ-1));
    f32x4 aa = *(const f32x4*)s, bb = *(const f32x4*)(s+4);
    v[0]+=aa.x; v[1]+=aa.y; v[2]+=aa.z; v[3]+=aa.w;
    v[4]+=bb.x; v[5]+=bb.y; v[6]+=bb.z; v[7]+=bb.w;
  }
  f32x4 b0 = *(const f32x4*)&bias[z*2048 + n], b1 = *(const f32x4*)&bias[z*2048 + n + 4];
  float bv[8] = {b0.x,b0.y,b0.z,b0.w,b1.x,b1.y,b1.z,b1.w};
  u16 w[8] __attribute__((aligned(16)));
  #pragma unroll
  for (int j = 0; j < 8; j++) w[j] = f2bf(v[j] + bv[j]);
  *(bf16x8*)&out[i] = *(bf16x8*)w;
}

// ---------------------------------------------------------------------------
// fp32 W[k][n] -> bf16 Wt[n][k]; wtrans6 batches up to 6 same-shape sources
// ---------------------------------------------------------------------------
struct P6 { const float* p[6]; };

__global__ __launch_bounds__(256)
void wtrans6(P6 srcs, int ldw, u16* __restrict__ Wt, long dstStride, int ldt)
{
  __shared__ u16 t[64][72];
  const float* W = srcs.p[blockIdx.z];
  u16* Wd = Wt + (long)blockIdx.z*dstStride;
  int tid = threadIdx.x, r = tid >> 2, c0 = (tid & 3)*16;
  long gr = (long)blockIdx.y*64 + r, gc = (long)blockIdx.x*64 + c0;
  #pragma unroll
  for (int u = 0; u < 16; u += 4) {
    f32x4 v = *(const f32x4*)&W[gr*ldw + gc + u];
    t[r][c0+u+0]=f2bf(v.x); t[r][c0+u+1]=f2bf(v.y);
    t[r][c0+u+2]=f2bf(v.z); t[r][c0+u+3]=f2bf(v.w);
  }
  __syncthreads();
  u16 o[16] __attribute__((aligned(16)));
  #pragma unroll
  for (int u = 0; u < 16; u++) o[u] = t[c0+u][r];
  u16* dst = &Wd[(long)(blockIdx.x*64 + r)*ldt + blockIdx.y*64 + c0];
  *(bf16x8*)&dst[0] = *(bf16x8*)&o[0];
  *(bf16x8*)&dst[8] = *(bf16x8*)&o[8];
}

__global__ __launch_bounds__(256)
void wtrans(const float* __restrict__ W, int ldw, u16* __restrict__ Wt, int ldt)
{
  __shared__ u16 t[64][72];
  int tid = threadIdx.x, r = tid >> 2, c0 = (tid & 3)*16;
  long gr = (long)blockIdx.y*64 + r, gc = (long)blockIdx.x*64 + c0;
  #pragma unroll
  for (int u = 0; u < 16; u += 4) {
    f32x4 v = *(const f32x4*)&W[gr*ldw + gc + u];
    t[r][c0+u+0]=f2bf(v.x); t[r][c0+u+1]=f2bf(v.y);
    t[r][c0+u+2]=f2bf(v.z); t[r][c0+u+3]=f2bf(v.w);
  }
  __syncthreads();
  u16 o[16] __attribute__((aligned(16)));
  #pragma unroll
  for (int u = 0; u < 16; u++) o[u] = t[c0+u][r];
  u16* dst = &Wt[(long)(blockIdx.x*64 + r)*ldt + blockIdx.y*64 + c0];
  *(bf16x8*)&dst[0] = *(bf16x8*)&o[0];
  *(bf16x8*)&dst[8] = *(bf16x8*)&o[8];
}

// bf16 V both branches -> Vt[128 heads][d][token]
__global__ __launch_bounds__(256)
void vtrans_both(const u16* __restrict__ QKVp, u16* __restrict__ Vt)
{
  __shared__ u16 t[64][72];
  int z = blockIdx.z;                          // 0..127
  int br = z >> 6, zz = z & 63, b = zz >> 4, h = zz & 15;
  const u16* src = QKVp + (long)br*QKVSZ + (long)b*SEQ*QKVN + h*HDIM + 2*DIM;
  u16* dst = Vt + (long)z*HDIM*SEQ;
  int tid = threadIdx.x, r = tid >> 2, c0 = (tid & 3)*16;
  int tok0 = blockIdx.x*64, d0 = blockIdx.y*64;
  #pragma unroll
  for (int u = 0; u < 16; u += 8) {
    bf16x8 v = *(const bf16x8*)&src[(long)(tok0+r)*QKVN + d0 + c0 + u];
    #pragma unroll
    for (int e = 0; e < 8; e++) t[r][c0+u+e] = (u16)v[e];
  }
  __syncthreads();
  u16 o[16] __attribute__((aligned(16)));
  #pragma unroll
  for (int u = 0; u < 16; u++) o[u] = t[c0+u][r];
  *(bf16x8*)&dst[(long)(d0+r)*SEQ + tok0 + c0]     = *(bf16x8*)&o[0];
  *(bf16x8*)&dst[(long)(d0+r)*SEQ + tok0 + c0 + 8] = *(bf16x8*)&o[8];
}

// ---------------------------------------------------------------------------
// small elementwise kernels
// ---------------------------------------------------------------------------
__global__ __launch_bounds__(256)
void f32_to_bf16(const float* __restrict__ in, u16* __restrict__ o, long n8)
{
  long i = (long)blockIdx.x*256 + threadIdx.x;
  if (i >= n8) return; i *= 8;
  f32x4 a = *(const f32x4*)&in[i], b = *(const f32x4*)&in[i+4];
  u16 w[8] __attribute__((aligned(16)));
  w[0]=f2bf(a.x);w[1]=f2bf(a.y);w[2]=f2bf(a.z);w[3]=f2bf(a.w);
  w[4]=f2bf(b.x);w[5]=f2bf(b.y);w[6]=f2bf(b.z);w[7]=f2bf(b.w);
  *(bf16x8*)&o[i] = *(bf16x8*)w;
}

__global__ __launch_bounds__(256)
void egather(const int* __restrict__ mods, const float* __restrict__ emb, u16* __restrict__ E)
{
  int i = blockIdx.x*256 + threadIdx.x;
  int row = i >> 3, j0 = (i & 7)*8;
  int m = mods[row]; if (m < 1) m = 1;
  const float* s = &emb[(long)m*64 + j0];
  f32x4 a = *(const f32x4*)s, b = *(const f32x4*)(s+4);
  u16 w[8] __attribute__((aligned(16)));
  w[0]=f2bf(a.x);w[1]=f2bf(a.y);w[2]=f2bf(a.z);w[3]=f2bf(a.w);
  w[4]=f2bf(b.x);w[5]=f2bf(b.y);w[6]=f2bf(b.z);w[7]=f2bf(b.w);
  *(bf16x8*)&E[(long)row*64 + j0] = *(bf16x8*)w;
}

__global__ __launch_bounds__(256)
void film_apply(const float* __restrict__ x, const u16* __restrict__ G,
                const u16* __restrict__ B, u16* __restrict__ y)
{
  long i = ((long)blockIdx.x*256 + threadIdx.x)*8;
  f32x4 x0 = *(const f32x4*)&x[i], x1 = *(const f32x4*)&x[i+4];
  bf16x8 g = *(const bf16x8*)&G[i], b = *(const bf16x8*)&B[i];
  float xv[8] = {x0.x,x0.y,x0.z,x0.w,x1.x,x1.y,x1.z,x1.w};
  u16 w[8] __attribute__((aligned(16)));
  #pragma unroll
  for (int e = 0; e < 8; e++)
    w[e] = f2bf((1.0f + bf2f((u16)g[e]))*xv[e] + bf2f((u16)b[e]));
  *(bf16x8*)&y[i] = *(bf16x8*)w;
}

__global__ __launch_bounds__(256)
void pack_bias(float* __restrict__ dst,
               const float* q_a, const float* k_a, const float* v_a,
               const float* q_e, const float* k_e, const float* v_e,
               const float* o_a, const float* o_e,
               const float* fg, const float* fb)
{
  int i = blockIdx.x*256 + threadIdx.x;
  if (i < 12288) {
    int br = i/6144, r = i - br*6144, sel = r >> 11, o = r & 2047;
    const float* s = br ? (sel==0?q_e:sel==1?k_e:v_e)
                        : (sel==0?q_a:sel==1?k_a:v_a);
    dst[i] = s[o];
  } else if (i < 16384) {
    int r = i - 12288; dst[i] = (r>>11) ? o_e[r&2047] : o_a[r&2047];
  } else {
    int r = i - 16384; dst[i] = (r>>11) ? fb[r&2047] : fg[r&2047];
  }
}

// ---------------------------------------------------------------------------
// LayerNorms
// ---------------------------------------------------------------------------
__global__ __launch_bounds__(256)
void ln_gate(const float* __restrict__ x, const u16* __restrict__ z0,
             const u16* __restrict__ z1, const float* __restrict__ ga,
             const float* __restrict__ g, const float* __restrict__ b,
             u16* __restrict__ h)
{
  __shared__ float red[8];
  long base = (long)blockIdx.x*DIM;
  int t8 = threadIdx.x*8, lane = threadIdx.x & 63, wid = threadIdx.x >> 6;
  float a0 = ga[0], a1 = ga[1];
  float mm = fmaxf(a0,a1), e0 = __expf(a0-mm), e1 = __expf(a1-mm);
  float w0 = e0/(e0+e1), w1 = e1/(e0+e1);
  f32x4 x0 = *(const f32x4*)&x[base+t8], x1 = *(const f32x4*)&x[base+t8+4];
  bf16x8 zi = *(const bf16x8*)&z0[base+t8], ze = *(const bf16x8*)&z1[base+t8];
  float xv[8] = {x0.x,x0.y,x0.z,x0.w,x1.x,x1.y,x1.z,x1.w};
  float v[8]; float s = 0.0f;
  #pragma unroll
  for (int j = 0; j < 8; j++) {
    v[j] = xv[j] + w0*bf2f((u16)zi[j]) + w1*bf2f((u16)ze[j]);
    s += v[j];
  }
  for (int o = 32; o; o >>= 1) s += __shfl_xor(s, o);
  if (lane == 0) red[wid] = s;
  __syncthreads();
  float mean = (red[0]+red[1]+red[2]+red[3])*(1.0f/DIM);
  float q = 0.0f;
  #pragma unroll
  for (int j = 0; j < 8; j++) { float d = v[j]-mean; q += d*d; }
  for (int o = 32; o; o >>= 1) q += __shfl_xor(q, o);
  if (lane == 0) red[4+wid] = q;
  __syncthreads();
  float inv = rsqrtf((red[4]+red[5]+red[6]+red[7])*(1.0f/DIM) + 1e-5f);
  f32x4 g0 = *(const f32x4*)&g[t8], g1 = *(const f32x4*)&g[t8+4];
  f32x4 b0 = *(const f32x4*)&b[t8], b1 = *(const f32x4*)&b[t8+4];
  float gv[8] = {g0.x,g0.y,g0.z,g0.w,g1.x,g1.y,g1.z,g1.w};
  float bv[8] = {b0.x,b0.y,b0.z,b0.w,b1.x,b1.y,b1.z,b1.w};
  u16 w[8] __attribute__((aligned(16)));
  #pragma unroll
  for (int j = 0; j < 8; j++) w[j] = f2bf((v[j]-mean)*inv*gv[j] + bv[j]);
  *(bf16x8*)&h[base+t8] = *(bf16x8*)w;
}

__global__ __launch_bounds__(256)
void ln_res(const u16* __restrict__ hin, const u16* __restrict__ y,
            const float* __restrict__ g, const float* __restrict__ b,
            float* __restrict__ out)
{
  __shared__ float red[8];
  long base = (long)blockIdx.x*DIM;
  int t8 = threadIdx.x*8, lane = threadIdx.x & 63, wid = threadIdx.x >> 6;
  bf16x8 hv = *(const bf16x8*)&hin[base+t8], yv = *(const bf16x8*)&y[base+t8];
  float v[8]; float s = 0.0f;
  #pragma unroll
  for (int j = 0; j < 8; j++) { v[j] = bf2f((u16)hv[j]) + bf2f((u16)yv[j]); s += v[j]; }
  for (int o = 32; o; o >>= 1) s += __shfl_xor(s, o);
  if (lane == 0) red[wid] = s;
  __syncthreads();
  float mean = (red[0]+red[1]+red[2]+red[3])*(1.0f/DIM);
  float q = 0.0f;
  #pragma unroll
  for (int j = 0; j < 8; j++) { float d = v[j]-mean; q += d*d; }
  for (int o = 32; o; o >>= 1) q += __shfl_xor(q, o);
  if (lane == 0) red[4+wid] = q;
  __syncthreads();
  float inv = rsqrtf((red[4]+red[5]+red[6]+red[7])*(1.0f/DIM) + 1e-5f);
  f32x4 g0 = *(const f32x4*)&g[t8], g1 = *(const f32x4*)&g[t8+4];
  f32x4 b0 = *(const f32x4*)&b[t8], b1 = *(const f32x4*)&b[t8+4];
  float gv[8] = {g0.x,g0.y,g0.z,g0.w,g1.x,g1.y,g1.z,g1.w};
  float bv[8] = {b0.x,b0.y,b0.z,b0.w,b1.x,b1.y,b1.z,b1.w};
  f32x4 o0, o1;
  #pragma unroll
  for (int j = 0; j < 4; j++) o0[j] = (v[j]-mean)*inv*gv[j] + bv[j];
  #pragma unroll
  for (int j = 0; j < 4; j++) o1[j] = (v[4+j]-mean)*inv*gv[4+j] + bv[4+j];
  *(f32x4*)&out[base+t8] = o0;
  *(f32x4*)&out[base+t8+4] = o1;
}

// ---------------------------------------------------------------------------
static void G4(hipStream_t st, const u16* A,int lda,long sAo,long sAi,
               const u16* B,int ldb,long sBo,long sBi,
               void* C,int ldc,long sCo,long sCi,int outbf,
               const float* bias,long sbias,int M,int N,int K,int batch,int hdiv,int relu)
{
  gemm4<<<dim3(N/128,M/128,batch),dim3(256),0,st>>>(
      A,lda,sAo,sAi,B,ldb,sBo,sBi,C,ldc,sCo,sCi,outbf,bias,sbias,K,hdiv,relu);
}
static void G4W(hipStream_t st, const u16* A,int lda,long sAo,long sAi,
                const u16* B,int ldb,long sBo,long sBi,
                u16* C,int ldc,long sCo,
                const float* bias,long sbias,int M,int N,int K,int batch,int hdiv,int relu)
{
  gemm4w<<<dim3(N/256,M/128,batch),dim3(256),0,st>>>(
      A,lda,sAo,sAi,B,ldb,sBo,sBi,C,ldc,sCo,bias,sbias,K,hdiv,relu);
}
static void G4W2(hipStream_t st, const u16* A,int lda,long sAo,long sAi,
                 const u16* B,int ldb,long sBo,long sBi,
                 u16* C,int ldc,long sCo,
                 const float* bias,long sbias,int M,int N,int K,int batch,int hdiv,int relu)
{
  gemm4w2<<<dim3(N/256,M/128,batch),dim3(256),0,st>>>(
      A,lda,sAo,sAi,B,ldb,sBo,sBi,C,ldc,sCo,bias,sbias,K,hdiv,relu);
}

extern "C" void kernel_launch(void* const* d_in, const int* in_sizes, int n_in,
                              void* d_out, int out_size, void* d_ws, size_t ws_size,
                              hipStream_t stream)
{
  const float* x          = (const float*)d_in[0];
  const float* mask_intra = (const float*)d_in[1];
  const float* mask_inter = (const float*)d_in[2];
  const int*   mods       = (const int*)  d_in[3];
  const float* film_emb   = (const float*)d_in[4];
  const float* film_gw    = (const float*)d_in[5];
  const float* film_gb    = (const float*)d_in[6];
  const float* film_bw    = (const float*)d_in[7];
  const float* film_bb    = (const float*)d_in[8];
  const float* gate_alpha = (const float*)d_in[9];
  const float* ln1_g = (const float*)d_in[10];
  const float* ln1_b = (const float*)d_in[11];
  const float* ln2_g = (const float*)d_in[12];
  const float* ln2_b = (const float*)d_in[13];
  const float* ffn_w1 = (const float*)d_in[14];
  const float* ffn_b1 = (const float*)d_in[15];
  const float* ffn_w2 = (const float*)d_in[16];
  const float* ffn_b2 = (const float*)d_in[17];
  const float* wq_a = (const float*)d_in[18]; const float* bq_a = (const float*)d_in[19];
  const float* wk_a = (const float*)d_in[20]; const float* bk_a = (const float*)d_in[21];
  const float* wv_a = (const float*)d_in[22]; const float* bv_a = (const float*)d_in[23];
  const float* wo_a = (const float*)d_in[24]; const float* bo_a = (const float*)d_in[25];
  const float* wq_e = (const float*)d_in[26]; const float* bq_e = (const float*)d_in[27];
  const float* wk_e = (const float*)d_in[28]; const float* bk_e = (const float*)d_in[29];
  const float* wv_e = (const float*)d_in[30]; const float* bv_e = (const float*)d_in[31];
  const float* wo_e = (const float*)d_in[32]; const float* bo_e = (const float*)d_in[33];

  // ---- lifetime-overlapped arena (audited R13) ----
  char* ws = (char*)d_ws;
  u16*   ybf  = (u16*)(ws);                      // 0..8Mi  y_intra (dead after QKV)
  u16*   xbf  = (u16*)(ws + (8L<<20));           // 8..16Mi x bf16 (dead after QKV)
  u16*   AO   = (u16*)(ws);                      // 0..16Mi attn out (PV -> out-proj)
  u16*   QKV  = (u16*)(ws + (16L<<20));          // 16..64Mi (dead after vtrans/qkprobs)
  u16*   Gf   = QKV;
  u16*   Bfm  = QKV + DSZ;
  u16*   zbuf = (u16*)(ws + (16L<<20));          // 16..32 (out-proj out; QKV dead)
  u16*   hbf  = (u16*)(ws + (32L<<20));          // 32..40
  u16*   Wst  = (u16*)(ws + (64L<<20));          // 64..96 weight staging
  u16*   Pall = (u16*)(ws + (96L<<20));          // 96..160 probs both branches
  u16*   mid  = (u16*)(ws + (96L<<20));          // 96..128 ffn mid (P dead by FFN)
  float* Pf2  = (float*)(ws + (128L<<20));       // 128..160 ffn2 partials (P dead)
  u16*   f2o  = (u16*)(ws + (16L<<20));          // 16..24 ffn2 out (zbuf dead after ln_gate)
  u16*   Vt   = (u16*)(ws + (160L<<20));         // 160..176 V^T both branches
  u16*   Ebuf = (u16*)(ws + (160L<<20));         //   (pre-Vt)
  u16*   Wfm  = (u16*)(ws + (161L<<20));         //   (pre-Vt)
  float* bpk  = (float*)(ws + (176L<<20));       // packed biases (80 KiB)

  // ---- conversions + packing ----
  f32_to_bf16<<<2048,256,0,stream>>>(x, xbf, DSZ/8);
  egather<<<64,256,0,stream>>>(mods, film_emb, Ebuf);
  {
    P6 pf; pf.p[0]=film_gw; pf.p[1]=film_bw;
    pf.p[2]=film_gw; pf.p[3]=film_gw; pf.p[4]=film_gw; pf.p[5]=film_gw;
    wtrans6<<<dim3(32,1,2),256,0,stream>>>(pf, DIM, Wfm, (long)DIM*64, 64);
  }
  pack_bias<<<80,256,0,stream>>>(bpk, bq_a,bk_a,bv_a, bq_e,bk_e,bv_e, bo_a,bo_e, film_gb,film_bb);

  // ---- FiLM: [G|B] = E @ [gw|bw] + bias (gemm4, z=2, K=64) ----
  G4(stream, Ebuf,64,0,0, Wfm,64,(long)DIM*64,0, Gf,DIM,DSZ,0,1,
     bpk+16384,2048, BTOK,DIM,64, 2,1, 0);
  film_apply<<<2048,256,0,stream>>>(x, Gf, Bfm, ybf);

  // ---- QKV both branches (gemm4w2: 48KB LDS -> 3 blk/CU, grid 768 packs) --
  {
    P6 pq; pq.p[0]=wq_a; pq.p[1]=wk_a; pq.p[2]=wv_a;
    pq.p[3]=wq_e; pq.p[4]=wk_e; pq.p[5]=wv_e;
    wtrans6<<<dim3(32,32,6),256,0,stream>>>(pq, DIM, Wst, (long)DIM*DIM, DIM);
  }
  G4W2(stream, ybf,DIM,DSZ,0, Wst,DIM,(long)QKVN*DIM,0, QKV,QKVN,QKVSZ,
       bpk,QKVN, BTOK,QKVN,DIM, 2,1, 0);

  // ---- attention: vtrans(both) ; qkprobs(both, BM=32) ; PV(both, gemm4) ----
  vtrans_both<<<dim3(8,2,128),256,0,stream>>>(QKV, Vt);
  qkprobs_both<<<dim3(128,16),dim3(256),0,stream>>>(QKV, mask_intra, mask_inter, Pall);
  G4(stream, Pall,SEQ,(long)16*SEQ*SEQ,(long)SEQ*SEQ,
     Vt,SEQ,(long)16*HDIM*SEQ,(long)HDIM*SEQ,
     AO,DIM,(long)SEQ*DIM,HDIM,1, nullptr,0,
     SEQ,HDIM,SEQ, 128,16, 0);

  // ---- out-proj (gemm4, z=2) -> z bf16 ----
  {
    P6 po; po.p[0]=wo_a; po.p[1]=wo_e;
    po.p[2]=wo_a; po.p[3]=wo_a; po.p[4]=wo_a; po.p[5]=wo_a;
    wtrans6<<<dim3(32,32,2),256,0,stream>>>(po, DIM, Wst, (long)DIM*DIM, DIM);
  }
  G4(stream, AO,DIM,DSZ,0, Wst,DIM,(long)DIM*DIM,0, zbuf,DIM,DSZ,0,1,
     bpk+12288,DIM, BTOK,DIM,DIM, 2,1, 0);

  // ---- gate + LN1 ----
  ln_gate<<<2048,256,0,stream>>>(x, zbuf, zbuf+DSZ, gate_alpha, ln1_g, ln1_b, hbf);

  // ---- FFN ----
  wtrans<<<dim3(128,32),256,0,stream>>>(ffn_w1, FFDIM, Wst, DIM);
  G4W(stream, hbf,DIM,0,0, Wst,DIM,0,0, mid,FFDIM,0,
      ffn_b1,0, BTOK,FFDIM,DIM, 1,1, 1);                                   // relu
  wtrans<<<dim3(32,128),256,0,stream>>>(ffn_w2, DIM, Wst, FFDIM);
  // FFN2 split-K x2 -> grid (16,16,2)=512 blocks
  G4(stream, mid,FFDIM,4096,0, Wst,FFDIM,4096,0, Pf2,DIM,DSZ,0,0,
     nullptr,0, BTOK,DIM,4096, 2,1, 0);
  redk<<<2048,256,0,stream>>>(Pf2, 2, ffn_b2, f2o);

  // ---- LN2 -> out ----
  ln_res<<<2048,256,0,stream>>>(hbf, f2o, ln2_g, ln2_b, (float*)d_out);
}